// Round 2
// baseline (864.641 us; speedup 1.0000x reference)
//
#include <hip/hip_runtime.h>
#include <hip/hip_bf16.h>

#define EE 768
#define HH 12
#define DD 64
#define BB 2
#define SS 2048
#define MM (BB*SS)   // 4096

static __device__ __forceinline__ unsigned short f2bf(float f) {
    unsigned int u = __float_as_uint(f);
    u += 0x7fffu + ((u >> 16) & 1u);      // round-to-nearest-even
    return (unsigned short)(u >> 16);
}
static __device__ __forceinline__ float bf2f(unsigned short us) {
    return __uint_as_float(((unsigned int)us) << 16);
}

// ---------------------------------------------------------------------------
// Kernel 1: fused QKV projection.  out = x @ W.T + b, split into heads,
// l2-normalize q,k rows (D=64) in-epilogue, fold SCALE=1/8 into q.
// grid (MM/64, 36): blockIdx.y 0-11 -> q(head h), 12-23 -> k, 24-35 -> v.
// Tile 64x64, BK=16, 256 threads, 4x4 micro-tile per thread.
// ---------------------------------------------------------------------------
__global__ __launch_bounds__(256) void qkv_proj_kernel(
    const float* __restrict__ xq, const float* __restrict__ xk, const float* __restrict__ xv,
    const float* __restrict__ Wq, const float* __restrict__ bq,
    const float* __restrict__ Wk, const float* __restrict__ bk,
    const float* __restrict__ Wv, const float* __restrict__ bv,
    unsigned short* __restrict__ qo, unsigned short* __restrict__ ko,
    unsigned short* __restrict__ vo)
{
    __shared__ float As[16][64];   // [kk][row]  (transposed for float4 reads)
    __shared__ float Bs[16][64];   // [kk][col]

    const int tid = threadIdx.x;
    const int bm  = blockIdx.x * 64;
    const int by  = blockIdx.y;
    const int proj = by / 12;            // 0=q 1=k 2=v
    const int h    = by % 12;
    const int n0r  = h * 64;             // column offset inside E

    const float* x    = (proj == 0) ? xq : (proj == 1) ? xk : xv;
    const float* W    = (proj == 0) ? Wq : (proj == 1) ? Wk : Wv;
    const float* bias = (proj == 0) ? bq : (proj == 1) ? bk : bv;
    unsigned short* dst = (proj == 0) ? qo : (proj == 1) ? ko : vo;

    const int lrow = tid >> 2;           // 0..63
    const int lkb  = (tid & 3) << 2;     // 0,4,8,12
    const int ty   = tid >> 4;           // 0..15 -> rows ty*4..+3
    const int tx   = tid & 15;           // 0..15 -> cols tx*4..+3

    float acc[4][4] = {};

    const float* aptr = x + (size_t)(bm  + lrow) * EE + lkb;
    const float* bptr = W + (size_t)(n0r + lrow) * EE + lkb;

    for (int kt = 0; kt < EE; kt += 16) {
        float4 av  = *(const float4*)(aptr + kt);
        float4 bv4 = *(const float4*)(bptr + kt);
        As[lkb+0][lrow] = av.x;  As[lkb+1][lrow] = av.y;
        As[lkb+2][lrow] = av.z;  As[lkb+3][lrow] = av.w;
        Bs[lkb+0][lrow] = bv4.x; Bs[lkb+1][lrow] = bv4.y;
        Bs[lkb+2][lrow] = bv4.z; Bs[lkb+3][lrow] = bv4.w;
        __syncthreads();
        #pragma unroll
        for (int kk = 0; kk < 16; ++kk) {
            float4 a = *(const float4*)&As[kk][ty*4];
            float4 b = *(const float4*)&Bs[kk][tx*4];
            float aa[4] = {a.x, a.y, a.z, a.w};
            float bb[4] = {b.x, b.y, b.z, b.w};
            #pragma unroll
            for (int i = 0; i < 4; ++i)
                #pragma unroll
                for (int j = 0; j < 4; ++j)
                    acc[i][j] += aa[i] * bb[j];
        }
        __syncthreads();
    }

    float cb[4];
    #pragma unroll
    for (int j = 0; j < 4; ++j) cb[j] = bias[n0r + tx*4 + j];

    #pragma unroll
    for (int i = 0; i < 4; ++i) {
        float vr[4];
        #pragma unroll
        for (int j = 0; j < 4; ++j) vr[j] = acc[i][j] + cb[j];
        if (proj < 2) {
            // row sum-of-squares across the 16 tx lanes sharing this row
            float ss = vr[0]*vr[0] + vr[1]*vr[1] + vr[2]*vr[2] + vr[3]*vr[3];
            #pragma unroll
            for (int msk = 1; msk < 16; msk <<= 1) ss += __shfl_xor(ss, msk);
            float inv = 1.0f / fmaxf(sqrtf(ss), 1e-6f);
            if (proj == 0) inv *= 0.125f;   // fold SCALE = D^-0.5 into q
            #pragma unroll
            for (int j = 0; j < 4; ++j) vr[j] *= inv;
        }
        const int mg    = bm + ty*4 + i;
        const int b_idx = mg >> 11;          // / SS
        const int s_idx = mg & (SS - 1);
        ushort4 pk;
        pk.x = f2bf(vr[0]); pk.y = f2bf(vr[1]);
        pk.z = f2bf(vr[2]); pk.w = f2bf(vr[3]);
        *(ushort4*)(dst + (((size_t)b_idx*HH + h)*SS + s_idx)*DD + tx*4) = pk;
    }
}

// ---------------------------------------------------------------------------
// Kernel 2: flash attention, fp32 compute over bf16 q/k/v [B*H, S, D].
// grid (SS/32, B*H), 256 threads. 32 q-rows per block, 64-key chunks,
// online softmax; acc in registers; ctx written fp32 [B, S, E].
// Thread map: ty=tid/16 -> rows {ty*2, ty*2+1}; tx=tid%16 -> cols tx*4..+3.
// ---------------------------------------------------------------------------
__global__ __launch_bounds__(256) void attn_kernel(
    const unsigned short* __restrict__ q, const unsigned short* __restrict__ k,
    const unsigned short* __restrict__ v, float* __restrict__ ctx)
{
    __shared__ float qT[64][32];   // [d][row]
    __shared__ float kT[64][64];   // [d][col]  (transposed)
    __shared__ float vs[64][64];   // [col][d]
    __shared__ float ps[32][64];   // [row][col] softmax numerators

    const int tid = threadIdx.x;
    const int bh  = blockIdx.y;
    const int t0  = blockIdx.x * 32;
    const int ty  = tid >> 4;
    const int tx  = tid & 15;
    const int r0  = ty*2, r1 = ty*2 + 1;

    {   // load q tile transposed (bf16 -> fp32)
        const int r  = tid >> 3;           // 0..31
        const int db = (tid & 7) << 3;     // 0..56
        const ushort4* qp = (const ushort4*)(q + ((size_t)bh*SS + t0 + r)*DD + db);
        ushort4 a = qp[0], b2 = qp[1];
        qT[db+0][r] = bf2f(a.x);  qT[db+1][r] = bf2f(a.y);
        qT[db+2][r] = bf2f(a.z);  qT[db+3][r] = bf2f(a.w);
        qT[db+4][r] = bf2f(b2.x); qT[db+5][r] = bf2f(b2.y);
        qT[db+6][r] = bf2f(b2.z); qT[db+7][r] = bf2f(b2.w);
    }

    float acc0[4] = {}, acc1[4] = {};
    float mrun0 = -1e30f, mrun1 = -1e30f;
    float lrun0 = 0.f,    lrun1 = 0.f;

    const int lc  = tid >> 2;          // 0..63 loader column
    const int ldb = (tid & 3) << 4;    // 0,16,32,48

    for (int s0 = 0; s0 < SS; s0 += 64) {
        __syncthreads();   // qT ready (iter 0) / prev PV done (later iters)

        const ushort4* kp = (const ushort4*)(k + ((size_t)bh*SS + s0 + lc)*DD + ldb);
        const ushort4* vp = (const ushort4*)(v + ((size_t)bh*SS + s0 + lc)*DD + ldb);
        #pragma unroll
        for (int u = 0; u < 4; ++u) {
            ushort4 k4 = kp[u];
            kT[ldb + u*4 + 0][lc] = bf2f(k4.x);
            kT[ldb + u*4 + 1][lc] = bf2f(k4.y);
            kT[ldb + u*4 + 2][lc] = bf2f(k4.z);
            kT[ldb + u*4 + 3][lc] = bf2f(k4.w);
            ushort4 v4 = vp[u];
            float4 vf; vf.x = bf2f(v4.x); vf.y = bf2f(v4.y);
            vf.z = bf2f(v4.z); vf.w = bf2f(v4.w);
            *(float4*)&vs[lc][ldb + u*4] = vf;
        }
        __syncthreads();

        // QK^T: scores for rows r0,r1 x cols tx*4..+3
        float sv0[4] = {}, sv1[4] = {};
        #pragma unroll 8
        for (int kk = 0; kk < 64; ++kk) {
            float2 qv = *(const float2*)&qT[kk][r0];
            float4 kv = *(const float4*)&kT[kk][tx*4];
            sv0[0] += qv.x*kv.x; sv0[1] += qv.x*kv.y;
            sv0[2] += qv.x*kv.z; sv0[3] += qv.x*kv.w;
            sv1[0] += qv.y*kv.x; sv1[1] += qv.y*kv.y;
            sv1[2] += qv.y*kv.z; sv1[3] += qv.y*kv.w;
        }

        // online softmax, row r0
        {
            float mx = fmaxf(fmaxf(sv0[0], sv0[1]), fmaxf(sv0[2], sv0[3]));
            #pragma unroll
            for (int msk = 1; msk < 16; msk <<= 1) mx = fmaxf(mx, __shfl_xor(mx, msk));
            float mnew = fmaxf(mrun0, mx);
            float al   = __expf(mrun0 - mnew);
            float p0 = __expf(sv0[0]-mnew), p1 = __expf(sv0[1]-mnew);
            float p2 = __expf(sv0[2]-mnew), p3 = __expf(sv0[3]-mnew);
            float rs = p0+p1+p2+p3;
            #pragma unroll
            for (int msk = 1; msk < 16; msk <<= 1) rs += __shfl_xor(rs, msk);
            lrun0 = lrun0*al + rs; mrun0 = mnew;
            acc0[0]*=al; acc0[1]*=al; acc0[2]*=al; acc0[3]*=al;
            *(float4*)&ps[r0][tx*4] = make_float4(p0, p1, p2, p3);
        }
        // online softmax, row r1
        {
            float mx = fmaxf(fmaxf(sv1[0], sv1[1]), fmaxf(sv1[2], sv1[3]));
            #pragma unroll
            for (int msk = 1; msk < 16; msk <<= 1) mx = fmaxf(mx, __shfl_xor(mx, msk));
            float mnew = fmaxf(mrun1, mx);
            float al   = __expf(mrun1 - mnew);
            float p0 = __expf(sv1[0]-mnew), p1 = __expf(sv1[1]-mnew);
            float p2 = __expf(sv1[2]-mnew), p3 = __expf(sv1[3]-mnew);
            float rs = p0+p1+p2+p3;
            #pragma unroll
            for (int msk = 1; msk < 16; msk <<= 1) rs += __shfl_xor(rs, msk);
            lrun1 = lrun1*al + rs; mrun1 = mnew;
            acc1[0]*=al; acc1[1]*=al; acc1[2]*=al; acc1[3]*=al;
            *(float4*)&ps[r1][tx*4] = make_float4(p0, p1, p2, p3);
        }
        __syncthreads();

        // PV: acc[r][d] += sum_c p[r][c] * v[c][d]
        #pragma unroll 4
        for (int c4 = 0; c4 < 16; ++c4) {
            float4 pp0 = *(const float4*)&ps[r0][c4*4];
            float4 pp1 = *(const float4*)&ps[r1][c4*4];
            float pa0[4] = {pp0.x, pp0.y, pp0.z, pp0.w};
            float pa1[4] = {pp1.x, pp1.y, pp1.z, pp1.w};
            #pragma unroll
            for (int u = 0; u < 4; ++u) {
                float4 vv = *(const float4*)&vs[c4*4 + u][tx*4];
                acc0[0] += pa0[u]*vv.x; acc0[1] += pa0[u]*vv.y;
                acc0[2] += pa0[u]*vv.z; acc0[3] += pa0[u]*vv.w;
                acc1[0] += pa1[u]*vv.x; acc1[1] += pa1[u]*vv.y;
                acc1[2] += pa1[u]*vv.z; acc1[3] += pa1[u]*vv.w;
            }
        }
    }

    const float inv0 = 1.0f / lrun0, inv1 = 1.0f / lrun1;
    const int b_idx = bh / HH, h = bh % HH;
    float* o0 = ctx + ((size_t)b_idx*SS + t0 + r0)*EE + h*DD + tx*4;
    float* o1 = ctx + ((size_t)b_idx*SS + t0 + r1)*EE + h*DD + tx*4;
    *(float4*)o0 = make_float4(acc0[0]*inv0, acc0[1]*inv0, acc0[2]*inv0, acc0[3]*inv0);
    *(float4*)o1 = make_float4(acc1[0]*inv1, acc1[1]*inv1, acc1[2]*inv1, acc1[3]*inv1);
}

// ---------------------------------------------------------------------------
// Kernel 3: output projection  out = ctx @ Wo.T + bo   (fp32)
// grid (MM/64, EE/64), same GEMM skeleton as kernel 1.
// ---------------------------------------------------------------------------
__global__ __launch_bounds__(256) void out_proj_kernel(
    const float* __restrict__ A, const float* __restrict__ W,
    const float* __restrict__ bias, float* __restrict__ out)
{
    __shared__ float As[16][64];
    __shared__ float Bs[16][64];

    const int tid = threadIdx.x;
    const int bm  = blockIdx.x * 64;
    const int n0  = blockIdx.y * 64;
    const int lrow = tid >> 2;
    const int lkb  = (tid & 3) << 2;
    const int ty   = tid >> 4;
    const int tx   = tid & 15;

    float acc[4][4] = {};
    const float* aptr = A + (size_t)(bm + lrow) * EE + lkb;
    const float* bptr = W + (size_t)(n0 + lrow) * EE + lkb;

    for (int kt = 0; kt < EE; kt += 16) {
        float4 av  = *(const float4*)(aptr + kt);
        float4 bv4 = *(const float4*)(bptr + kt);
        As[lkb+0][lrow] = av.x;  As[lkb+1][lrow] = av.y;
        As[lkb+2][lrow] = av.z;  As[lkb+3][lrow] = av.w;
        Bs[lkb+0][lrow] = bv4.x; Bs[lkb+1][lrow] = bv4.y;
        Bs[lkb+2][lrow] = bv4.z; Bs[lkb+3][lrow] = bv4.w;
        __syncthreads();
        #pragma unroll
        for (int kk = 0; kk < 16; ++kk) {
            float4 a = *(const float4*)&As[kk][ty*4];
            float4 b = *(const float4*)&Bs[kk][tx*4];
            float aa[4] = {a.x, a.y, a.z, a.w};
            float bb[4] = {b.x, b.y, b.z, b.w};
            #pragma unroll
            for (int i = 0; i < 4; ++i)
                #pragma unroll
                for (int j = 0; j < 4; ++j)
                    acc[i][j] += aa[i] * bb[j];
        }
        __syncthreads();
    }

    float cb[4];
    #pragma unroll
    for (int j = 0; j < 4; ++j) cb[j] = bias[n0 + tx*4 + j];
    #pragma unroll
    for (int i = 0; i < 4; ++i) {
        float4 o;
        o.x = acc[i][0] + cb[0]; o.y = acc[i][1] + cb[1];
        o.z = acc[i][2] + cb[2]; o.w = acc[i][3] + cb[3];
        *(float4*)(out + (size_t)(bm + ty*4 + i)*EE + n0 + tx*4) = o;
    }
}

// ---------------------------------------------------------------------------
extern "C" void kernel_launch(void* const* d_in, const int* in_sizes, int n_in,
                              void* d_out, int out_size, void* d_ws, size_t ws_size,
                              hipStream_t stream)
{
    const float* query = (const float*)d_in[0];
    const float* key   = (const float*)d_in[1];
    const float* value = (const float*)d_in[2];
    const float* Wq = (const float*)d_in[3];
    const float* bq = (const float*)d_in[4];
    const float* Wk = (const float*)d_in[5];
    const float* bk = (const float*)d_in[6];
    const float* Wv = (const float*)d_in[7];
    const float* bv = (const float*)d_in[8];
    const float* Wo = (const float*)d_in[9];
    const float* bo = (const float*)d_in[10];
    float* out = (float*)d_out;

    // workspace: q,k,v bf16 [B,H,S,D] (6 MB each) + ctx fp32 [B,S,E] (12.6 MB)
    const size_t NQ = (size_t)BB * HH * SS * DD;   // 3,145,728
    unsigned short* qws = (unsigned short*)d_ws;
    unsigned short* kws = qws + NQ;
    unsigned short* vws = kws + NQ;
    float* ctx = (float*)(vws + NQ);               // 16B-aligned (offset 18 MiB)

    qkv_proj_kernel<<<dim3(MM/64, 36), 256, 0, stream>>>(
        query, key, value, Wq, bq, Wk, bk, Wv, bv, qws, kws, vws);
    attn_kernel<<<dim3(SS/32, BB*HH), 256, 0, stream>>>(qws, kws, vws, ctx);
    out_proj_kernel<<<dim3(MM/64, EE/64), 256, 0, stream>>>(ctx, Wo, bo, out);
}

// Round 3
// 246.181 us; speedup vs baseline: 3.5122x; 3.5122x over previous
//
#include <hip/hip_runtime.h>
#include <hip/hip_bf16.h>

#define EE 768
#define HH 12
#define DD 64
#define BB 2
#define SS 2048
#define MM (BB*SS)   // 4096

typedef short short8 __attribute__((ext_vector_type(8)));   // 8 bf16 = 4 VGPR (MFMA A/B frag)
typedef float f32x4 __attribute__((ext_vector_type(4)));    // MFMA C/D frag

static __device__ __forceinline__ unsigned short f2bf(float f) {
    unsigned int u = __float_as_uint(f);
    u += 0x7fffu + ((u >> 16) & 1u);      // round-to-nearest-even
    return (unsigned short)(u >> 16);
}

// Swizzled byte offset inside a [R][64] bf16 LDS tile (128B rows, 8x16B chunks).
// chunk' = chunk ^ (row&7): spreads the 16B-chunk column across 8 bank-quads
// (sec 6 G4 canonical fix); b128 frag reads then run at the 8-cycle BW floor.
static __device__ __forceinline__ int swz(int row, int chunk) {
    return row * 128 + ((chunk ^ (row & 7)) << 4);
}

// ---------------------------------------------------------------------------
// Kernel 1: QKV projection, MFMA.  C[m][n] = x[m][:] . W[n][:]  (+bias)
// grid (MM/128, 36): by 0-11 q(head), 12-23 k, 24-35 v.
// BM=128 BN=64 BK=64, 256 thr = 4 waves (2M x 2N), per-wave 64x32 (Mrep4,Nrep2).
// Epilogue: +bias; q/k: l2-norm over the 64-wide head (SCALE folded into q),
// store bf16 [bh][s][d].  v: store TRANSPOSED bf16 [bh][d][s] via LDS.
// ---------------------------------------------------------------------------
__global__ __launch_bounds__(256) void qkv_mfma_kernel(
    const float* __restrict__ xq, const float* __restrict__ xk, const float* __restrict__ xv,
    const float* __restrict__ Wq, const float* __restrict__ bq,
    const float* __restrict__ Wk, const float* __restrict__ bk,
    const float* __restrict__ Wv, const float* __restrict__ bv,
    unsigned short* __restrict__ qo, unsigned short* __restrict__ ko,
    unsigned short* __restrict__ vo)
{
    __shared__ short As[128 * 64];   // 16 KB, swizzled [row][k]
    __shared__ short Bs[64 * 64];    //  8 KB, swizzled [n][k]
    __shared__ float ssq[2][128];    //  1 KB cross-wave row sum-of-squares

    const int tid = threadIdx.x;
    const int bm  = blockIdx.x * 128;
    const int by  = blockIdx.y;
    const int proj = by / 12;
    const int h    = by % 12;
    const int n0r  = h * 64;

    const float* x    = (proj == 0) ? xq : (proj == 1) ? xk : xv;
    const float* W    = (proj == 0) ? Wq : (proj == 1) ? Wk : Wv;
    const float* bias = (proj == 0) ? bq : (proj == 1) ? bk : bv;

    const int w  = tid >> 6;        // wave 0..3
    const int l  = tid & 63;
    const int c  = l & 15;          // frag col/row lane part
    const int g  = l >> 4;          // frag k-group
    const int wm = w >> 1;          // 0..1 (M half)
    const int wn = w & 1;           // 0..1 (N half)

    f32x4 acc[4][2] = {};

    for (int kt = 0; kt < EE; kt += 64) {
        __syncthreads();   // protect LDS reuse (no-op first iter)
        // stage A: 128 rows x 8 chunks = 1024 chunks, 4/thread
        #pragma unroll
        for (int i = 0; i < 4; ++i) {
            const int cid = tid + 256 * i;
            const int row = cid >> 3, ch = cid & 7;
            const float* ga = x + (size_t)(bm + row) * EE + kt + ch * 8;
            float4 f0 = *(const float4*)ga;
            float4 f1 = *(const float4*)(ga + 4);
            short8 pk;
            pk[0]=f2bf(f0.x); pk[1]=f2bf(f0.y); pk[2]=f2bf(f0.z); pk[3]=f2bf(f0.w);
            pk[4]=f2bf(f1.x); pk[5]=f2bf(f1.y); pk[6]=f2bf(f1.z); pk[7]=f2bf(f1.w);
            *(short8*)((char*)As + swz(row, ch)) = pk;
        }
        // stage B: 64 rows x 8 chunks = 512 chunks, 2/thread
        #pragma unroll
        for (int i = 0; i < 2; ++i) {
            const int cid = tid + 256 * i;
            const int row = cid >> 3, ch = cid & 7;
            const float* ga = W + (size_t)(n0r + row) * EE + kt + ch * 8;
            float4 f0 = *(const float4*)ga;
            float4 f1 = *(const float4*)(ga + 4);
            short8 pk;
            pk[0]=f2bf(f0.x); pk[1]=f2bf(f0.y); pk[2]=f2bf(f0.z); pk[3]=f2bf(f0.w);
            pk[4]=f2bf(f1.x); pk[5]=f2bf(f1.y); pk[6]=f2bf(f1.z); pk[7]=f2bf(f1.w);
            *(short8*)((char*)Bs + swz(row, ch)) = pk;
        }
        __syncthreads();

        #pragma unroll
        for (int ks = 0; ks < 2; ++ks) {
            short8 bf[2], af[4];
            #pragma unroll
            for (int nt = 0; nt < 2; ++nt) {
                const int row = wn * 32 + nt * 16 + c;
                bf[nt] = *(const short8*)((const char*)Bs + swz(row, ks * 4 + g));
            }
            #pragma unroll
            for (int mt = 0; mt < 4; ++mt) {
                const int row = wm * 64 + mt * 16 + c;
                af[mt] = *(const short8*)((const char*)As + swz(row, ks * 4 + g));
            }
            #pragma unroll
            for (int mt = 0; mt < 4; ++mt)
                #pragma unroll
                for (int nt = 0; nt < 2; ++nt)
                    acc[mt][nt] = __builtin_amdgcn_mfma_f32_16x16x32_bf16(
                        af[mt], bf[nt], acc[mt][nt], 0, 0, 0);
        }
    }
    __syncthreads();

    float bb[2];
    #pragma unroll
    for (int nt = 0; nt < 2; ++nt) bb[nt] = bias[n0r + wn * 32 + nt * 16 + c];

    const int bidx = bm >> 11;          // batch
    const int sbase = bm & (SS - 1);

    if (proj < 2) {
        // add bias, l2-normalize rows of the 64-wide head, store bf16 [bh][s][d]
        f32x4 vr[4][2];
        f32x4 ssp[4];
        #pragma unroll
        for (int mt = 0; mt < 4; ++mt) {
            #pragma unroll
            for (int nt = 0; nt < 2; ++nt)
                #pragma unroll
                for (int j = 0; j < 4; ++j)
                    vr[mt][nt][j] = acc[mt][nt][j] + bb[nt];
            #pragma unroll
            for (int j = 0; j < 4; ++j)
                ssp[mt][j] = vr[mt][0][j]*vr[mt][0][j] + vr[mt][1][j]*vr[mt][1][j];
            #pragma unroll
            for (int j = 0; j < 4; ++j) {
                float s = ssp[mt][j];
                #pragma unroll
                for (int msk = 1; msk < 16; msk <<= 1) s += __shfl_xor(s, msk);
                ssp[mt][j] = s;   // 32-col partial (this wave-half)
            }
        }
        if (c == 0) {
            #pragma unroll
            for (int mt = 0; mt < 4; ++mt)
                #pragma unroll
                for (int j = 0; j < 4; ++j)
                    ssq[wn][wm * 64 + mt * 16 + g * 4 + j] = ssp[mt][j];
        }
        __syncthreads();
        unsigned short* dst = (proj == 0) ? qo : ko;
        const float fold = (proj == 0) ? 0.125f : 1.0f;
        #pragma unroll
        for (int mt = 0; mt < 4; ++mt) {
            #pragma unroll
            for (int j = 0; j < 4; ++j) {
                const int rloc = wm * 64 + mt * 16 + g * 4 + j;
                const float ss = ssq[0][rloc] + ssq[1][rloc];
                const float inv = fold / fmaxf(sqrtf(ss), 1e-6f);
                const size_t base =
                    ((size_t)(bidx * HH + h) * SS + sbase + rloc) * DD;
                #pragma unroll
                for (int nt = 0; nt < 2; ++nt)
                    dst[base + wn * 32 + nt * 16 + c] = f2bf(vr[mt][nt][j] * inv);
            }
        }
    } else {
        // V: +bias, transpose through LDS (reuse As as bf16 [128 s][64 d]),
        // store bf16 vT [bh][d][s]
        #pragma unroll
        for (int mt = 0; mt < 4; ++mt)
            #pragma unroll
            for (int nt = 0; nt < 2; ++nt)
                #pragma unroll
                for (int j = 0; j < 4; ++j) {
                    const int row = wm * 64 + mt * 16 + g * 4 + j;
                    const int col = wn * 32 + nt * 16 + c;
                    As[row * 64 + col] = (short)f2bf(acc[mt][nt][j] + bb[nt]);
                }
        __syncthreads();
        const int d  = tid & 63;
        const int sb = (tid >> 6) * 32;
        unsigned short* dstp = vo + ((size_t)(bidx * HH + h) * DD + d) * SS + sbase + sb;
        #pragma unroll
        for (int grp = 0; grp < 4; ++grp) {
            unsigned int wds[4];
            #pragma unroll
            for (int e = 0; e < 4; ++e) {
                unsigned short u0 = (unsigned short)As[(sb + grp * 8 + 2 * e)     * 64 + d];
                unsigned short u1 = (unsigned short)As[(sb + grp * 8 + 2 * e + 1) * 64 + d];
                wds[e] = (unsigned int)u0 | ((unsigned int)u1 << 16);
            }
            int4 pk = make_int4((int)wds[0], (int)wds[1], (int)wds[2], (int)wds[3]);
            *(int4*)(dstp + grp * 8) = pk;
        }
    }
}

// ---------------------------------------------------------------------------
// Kernel 2: flash attention, bf16 MFMA.  q,k [bh][s][d]; v TRANSPOSED [bh][d][s].
// grid (SS/64, B*H), 256 thr = 4 waves; wave owns 16 q-rows; KVBLK=64.
// No max-tracking: |score| <= ~0.126 (l2-normed q,k x SCALE) => exp is safe.
// S/P layout: C/D frag row=(l>>4)*4+reg, col=l&15 (m89/m91-verified).
// ---------------------------------------------------------------------------
__global__ __launch_bounds__(256) void attn_mfma_kernel(
    const unsigned short* __restrict__ q, const unsigned short* __restrict__ k,
    const unsigned short* __restrict__ vT, unsigned short* __restrict__ ctx)
{
    __shared__ short Ks[64 * 64];        // [key][d] swizzled, 8 KB
    __shared__ short Vs[64 * 64];        // [d][key] swizzled, 8 KB
    __shared__ short Ps[4 * 16 * 64];    // per-wave [row][key] swizzled, 8 KB

    const int tid = threadIdx.x;
    const int bh  = blockIdx.y;
    const int w   = tid >> 6;
    const int l   = tid & 63;
    const int c   = l & 15;
    const int g   = l >> 4;
    const int qr0 = blockIdx.x * 64 + w * 16;

    // Q A-frags in registers, reused across all KV tiles
    const unsigned short* qg = q + ((size_t)bh * SS + qr0 + c) * DD;
    short8 aq[2];
    aq[0] = *(const short8*)(qg + g * 8);
    aq[1] = *(const short8*)(qg + 32 + g * 8);

    short* Psw = Ps + w * (16 * 64);

    f32x4 o[4] = {};
    f32x4 lr = {0.f, 0.f, 0.f, 0.f};

    for (int s0 = 0; s0 < SS; s0 += 64) {
        __syncthreads();   // prev tile's frag reads done
        // stage K tile: 512 chunks, 2/thread
        #pragma unroll
        for (int i = 0; i < 2; ++i) {
            const int cid = tid + 256 * i;
            const int key = cid >> 3, ch = cid & 7;
            int4 kv4 = *(const int4*)(k + ((size_t)bh * SS + s0 + key) * DD + ch * 8);
            *(int4*)((char*)Ks + swz(key, ch)) = kv4;
        }
        // stage V tile from vT: rows are d, cols are keys
        #pragma unroll
        for (int i = 0; i < 2; ++i) {
            const int cid = tid + 256 * i;
            const int d = cid >> 3, ch = cid & 7;
            int4 vv4 = *(const int4*)(vT + ((size_t)bh * DD + d) * SS + s0 + ch * 8);
            *(int4*)((char*)Vs + swz(d, ch)) = vv4;
        }
        __syncthreads();

        // QK^T: 4 key-tiles x 2 k-steps
        f32x4 sc[4] = {};
        #pragma unroll
        for (int ks = 0; ks < 2; ++ks)
            #pragma unroll
            for (int nt = 0; nt < 4; ++nt) {
                const int row = nt * 16 + c;    // key
                short8 kf = *(const short8*)((const char*)Ks + swz(row, ks * 4 + g));
                sc[nt] = __builtin_amdgcn_mfma_f32_16x16x32_bf16(aq[ks], kf, sc[nt], 0, 0, 0);
            }

        // softmax numerators (no max subtraction needed; |sc| <= ~0.13)
        f32x4 p[4];
        #pragma unroll
        for (int nt = 0; nt < 4; ++nt)
            #pragma unroll
            for (int j = 0; j < 4; ++j)
                p[nt][j] = __expf(sc[nt][j]);
        f32x4 rs;
        #pragma unroll
        for (int j = 0; j < 4; ++j) {
            float r = p[0][j] + p[1][j] + p[2][j] + p[3][j];
            #pragma unroll
            for (int msk = 1; msk < 16; msk <<= 1) r += __shfl_xor(r, msk);
            rs[j] = r;
        }
        #pragma unroll
        for (int j = 0; j < 4; ++j) lr[j] += rs[j];

        // P -> bf16 -> per-wave LDS (swizzled [row][key])
        #pragma unroll
        for (int nt = 0; nt < 4; ++nt)
            #pragma unroll
            for (int j = 0; j < 4; ++j) {
                const int row = g * 4 + j;
                const int elem = row * 64 + (((nt * 2 + (c >> 3)) ^ (row & 7)) << 3) + (c & 7);
                Psw[elem] = (short)f2bf(p[nt][j]);
            }

        // PV: o[dt] += P . V
        #pragma unroll
        for (int ks = 0; ks < 2; ++ks) {
            short8 pa = *(const short8*)((const char*)Psw + swz(c, ks * 4 + g));
            #pragma unroll
            for (int dt = 0; dt < 4; ++dt) {
                const int row = dt * 16 + c;    // d
                short8 vf = *(const short8*)((const char*)Vs + swz(row, ks * 4 + g));
                o[dt] = __builtin_amdgcn_mfma_f32_16x16x32_bf16(pa, vf, o[dt], 0, 0, 0);
            }
        }
    }

    // epilogue: divide by denom, store ctx bf16 [b][s][e]
    const int bidx = bh / HH, h = bh % HH;
    f32x4 invl;
    #pragma unroll
    for (int j = 0; j < 4; ++j) invl[j] = 1.0f / lr[j];
    #pragma unroll
    for (int j = 0; j < 4; ++j) {
        const int sg = qr0 + g * 4 + j;
        unsigned short* op = ctx + ((size_t)bidx * SS + sg) * EE + h * DD + c;
        #pragma unroll
        for (int dt = 0; dt < 4; ++dt)
            op[dt * 16] = f2bf(o[dt][j] * invl[j]);
    }
}

// ---------------------------------------------------------------------------
// Kernel 3: output projection, MFMA.  out = ctx(bf16) @ Wo.T + bo  (fp32 out)
// grid (MM/128, EE/64), same tile structure as kernel 1.
// ---------------------------------------------------------------------------
__global__ __launch_bounds__(256) void out_mfma_kernel(
    const unsigned short* __restrict__ A, const float* __restrict__ W,
    const float* __restrict__ bias, float* __restrict__ out)
{
    __shared__ short As[128 * 64];
    __shared__ short Bs[64 * 64];

    const int tid = threadIdx.x;
    const int bm  = blockIdx.x * 128;
    const int n0  = blockIdx.y * 64;

    const int w  = tid >> 6;
    const int l  = tid & 63;
    const int c  = l & 15;
    const int g  = l >> 4;
    const int wm = w >> 1;
    const int wn = w & 1;

    f32x4 acc[4][2] = {};

    for (int kt = 0; kt < EE; kt += 64) {
        __syncthreads();
        #pragma unroll
        for (int i = 0; i < 4; ++i) {
            const int cid = tid + 256 * i;
            const int row = cid >> 3, ch = cid & 7;
            int4 a8 = *(const int4*)(A + (size_t)(bm + row) * EE + kt + ch * 8);
            *(int4*)((char*)As + swz(row, ch)) = a8;
        }
        #pragma unroll
        for (int i = 0; i < 2; ++i) {
            const int cid = tid + 256 * i;
            const int row = cid >> 3, ch = cid & 7;
            const float* ga = W + (size_t)(n0 + row) * EE + kt + ch * 8;
            float4 f0 = *(const float4*)ga;
            float4 f1 = *(const float4*)(ga + 4);
            short8 pk;
            pk[0]=f2bf(f0.x); pk[1]=f2bf(f0.y); pk[2]=f2bf(f0.z); pk[3]=f2bf(f0.w);
            pk[4]=f2bf(f1.x); pk[5]=f2bf(f1.y); pk[6]=f2bf(f1.z); pk[7]=f2bf(f1.w);
            *(short8*)((char*)Bs + swz(row, ch)) = pk;
        }
        __syncthreads();

        #pragma unroll
        for (int ks = 0; ks < 2; ++ks) {
            short8 bf[2], af[4];
            #pragma unroll
            for (int nt = 0; nt < 2; ++nt) {
                const int row = wn * 32 + nt * 16 + c;
                bf[nt] = *(const short8*)((const char*)Bs + swz(row, ks * 4 + g));
            }
            #pragma unroll
            for (int mt = 0; mt < 4; ++mt) {
                const int row = wm * 64 + mt * 16 + c;
                af[mt] = *(const short8*)((const char*)As + swz(row, ks * 4 + g));
            }
            #pragma unroll
            for (int mt = 0; mt < 4; ++mt)
                #pragma unroll
                for (int nt = 0; nt < 2; ++nt)
                    acc[mt][nt] = __builtin_amdgcn_mfma_f32_16x16x32_bf16(
                        af[mt], bf[nt], acc[mt][nt], 0, 0, 0);
        }
    }

    float bb[2];
    #pragma unroll
    for (int nt = 0; nt < 2; ++nt) bb[nt] = bias[n0 + wn * 32 + nt * 16 + c];

    #pragma unroll
    for (int mt = 0; mt < 4; ++mt)
        #pragma unroll
        for (int j = 0; j < 4; ++j) {
            const int row = bm + wm * 64 + mt * 16 + g * 4 + j;
            float* op = out + (size_t)row * EE + n0 + wn * 32 + c;
            #pragma unroll
            for (int nt = 0; nt < 2; ++nt)
                op[nt * 16] = acc[mt][nt][j] + bb[nt];
        }
}

// ---------------------------------------------------------------------------
extern "C" void kernel_launch(void* const* d_in, const int* in_sizes, int n_in,
                              void* d_out, int out_size, void* d_ws, size_t ws_size,
                              hipStream_t stream)
{
    const float* query = (const float*)d_in[0];
    const float* key   = (const float*)d_in[1];
    const float* value = (const float*)d_in[2];
    const float* Wq = (const float*)d_in[3];
    const float* bq = (const float*)d_in[4];
    const float* Wk = (const float*)d_in[5];
    const float* bk = (const float*)d_in[6];
    const float* Wv = (const float*)d_in[7];
    const float* bv = (const float*)d_in[8];
    const float* Wo = (const float*)d_in[9];
    const float* bo = (const float*)d_in[10];
    float* out = (float*)d_out;

    // workspace: q,k [bh][s][d], vT [bh][d][s] bf16 (6 MB each) + ctx bf16 (6 MB)
    const size_t NQ = (size_t)BB * HH * SS * DD;
    unsigned short* qws  = (unsigned short*)d_ws;
    unsigned short* kws  = qws + NQ;
    unsigned short* vtws = kws + NQ;
    unsigned short* ctx  = vtws + NQ;

    qkv_mfma_kernel<<<dim3(MM/128, 36), 256, 0, stream>>>(
        query, key, value, Wq, bq, Wk, bk, Wv, bv, qws, kws, vtws);
    attn_mfma_kernel<<<dim3(SS/64, BB*HH), 256, 0, stream>>>(qws, kws, vtws, ctx);
    out_mfma_kernel<<<dim3(MM/128, EE/64), 256, 0, stream>>>(ctx, Wo, bo, out);
}

// Round 5
// 235.172 us; speedup vs baseline: 3.6766x; 1.0468x over previous
//
#include <hip/hip_runtime.h>
#include <hip/hip_bf16.h>

#define EE 768
#define HH 12
#define DD 64
#define BB 2
#define SS 2048
#define MM (BB*SS)          // 4096
#define NT (MM*EE)          // 3,145,728 elements (also B*H*S*D)
#define NW (EE*EE)          // 589,824

typedef short short8 __attribute__((ext_vector_type(8)));   // 8 bf16 = 4 VGPR (MFMA A/B frag)
typedef float f32x4 __attribute__((ext_vector_type(4)));    // MFMA C/D frag

static __device__ __forceinline__ unsigned short f2bf(float f) {
    unsigned int u = __float_as_uint(f);
    u += 0x7fffu + ((u >> 16) & 1u);      // round-to-nearest-even
    return (unsigned short)(u >> 16);
}

// async 16B global->LDS. LDS dest = wave-uniform base + lane*16 (HW rule).
static __device__ __forceinline__ void gl16(const void* g, void* l) {
    __builtin_amdgcn_global_load_lds(
        (const __attribute__((address_space(1))) unsigned int*)g,
        (__attribute__((address_space(3))) unsigned int*)l, 16, 0, 0);
}

// Swizzled byte offset in a [R][64] bf16 LDS tile (128B rows, 8x16B chunks).
// Staging pre-swizzles the per-lane GLOBAL source chunk ((l&7)^(l>>3)) so the
// linear gl16 dest holds swizzled content; reads via swz() are conflict-free
// (rule #21: both-sides-or-neither).
static __device__ __forceinline__ int swz(int row, int chunk) {
    return row * 128 + ((chunk ^ (row & 7)) << 4);
}

// ---------------------------------------------------------------------------
// fp32 -> bf16 pre-convert (memory-bound). One float4 -> ushort4 per thread.
// ---------------------------------------------------------------------------
__global__ __launch_bounds__(256) void cvt_x_kernel(
    const float* __restrict__ a0, const float* __restrict__ a1, const float* __restrict__ a2,
    unsigned short* __restrict__ o0, unsigned short* __restrict__ o1, unsigned short* __restrict__ o2)
{
    const float* s = (blockIdx.y == 0) ? a0 : (blockIdx.y == 1) ? a1 : a2;
    unsigned short* d = (blockIdx.y == 0) ? o0 : (blockIdx.y == 1) ? o1 : o2;
    const int idx = blockIdx.x * 256 + threadIdx.x;
    float4 f = ((const float4*)s)[idx];
    ushort4 u;
    u.x = f2bf(f.x); u.y = f2bf(f.y); u.z = f2bf(f.z); u.w = f2bf(f.w);
    ((ushort4*)d)[idx] = u;
}

__global__ __launch_bounds__(256) void cvt_w_kernel(
    const float* __restrict__ a0, const float* __restrict__ a1,
    const float* __restrict__ a2, const float* __restrict__ a3,
    unsigned short* __restrict__ o0, unsigned short* __restrict__ o1,
    unsigned short* __restrict__ o2, unsigned short* __restrict__ o3)
{
    const int y = blockIdx.y;
    const float* s = (y == 0) ? a0 : (y == 1) ? a1 : (y == 2) ? a2 : a3;
    unsigned short* d = (y == 0) ? o0 : (y == 1) ? o1 : (y == 2) ? o2 : o3;
    const int idx = blockIdx.x * 256 + threadIdx.x;
    float4 f = ((const float4*)s)[idx];
    ushort4 u;
    u.x = f2bf(f.x); u.y = f2bf(f.y); u.z = f2bf(f.z); u.w = f2bf(f.w);
    ((ushort4*)d)[idx] = u;
}

// ---------------------------------------------------------------------------
// Kernel 1: QKV projection, MFMA, bf16 inputs, global_load_lds staging.
// grid (MM/128, 36): by 0-11 q(head), 12-23 k, 24-35 v.
// BM=128 BN=64 BK=64, 256 thr = 4 waves (2Mx2N), per-wave 64x32.
// Epilogue: +bias; q/k l2-norm over head (SCALE folded into q) -> bf16 [bh][s][d];
// v -> transposed bf16 [bh][d][s] via LDS.
// ---------------------------------------------------------------------------
__global__ __launch_bounds__(256) void qkv_mfma_kernel(
    const unsigned short* __restrict__ xq, const unsigned short* __restrict__ xk,
    const unsigned short* __restrict__ xv,
    const unsigned short* __restrict__ Wq, const float* __restrict__ bq,
    const unsigned short* __restrict__ Wk, const float* __restrict__ bk,
    const unsigned short* __restrict__ Wv, const float* __restrict__ bv,
    unsigned short* __restrict__ qo, unsigned short* __restrict__ ko,
    unsigned short* __restrict__ vo)
{
    __shared__ short As[128 * 64];   // 16 KB
    __shared__ short Bs[64 * 64];    //  8 KB
    __shared__ float ssq[2][128];    //  1 KB

    const int tid = threadIdx.x;
    const int bm  = blockIdx.x * 128;
    const int by  = blockIdx.y;
    const int proj = by / 12;
    const int h    = by % 12;
    const int n0r  = h * 64;

    const unsigned short* x = (proj == 0) ? xq : (proj == 1) ? xk : xv;
    const unsigned short* W = (proj == 0) ? Wq : (proj == 1) ? Wk : Wv;
    const float* bias       = (proj == 0) ? bq : (proj == 1) ? bk : bv;

    const int w  = tid >> 6;
    const int l  = tid & 63;
    const int c  = l & 15;
    const int g  = l >> 4;
    const int wm = w >> 1;
    const int wn = w & 1;
    const int lr8 = l >> 3;                 // 0..7: row-in-issue
    const int lc8 = (l & 7) ^ lr8;          // pre-swizzled source chunk

    f32x4 acc[4][2] = {};

    for (int kt = 0; kt < EE; kt += 64) {
        __syncthreads();   // prev compute done before overwrite
        #pragma unroll
        for (int i = 0; i < 4; ++i) {       // A: 16 KB = 16 issues, 4/wave
            const int t = w * 4 + i;
            const int row = t * 8 + lr8;
            gl16(x + (size_t)(bm + row) * EE + kt + lc8 * 8,
                 (unsigned short*)As + t * 512);
        }
        #pragma unroll
        for (int i = 0; i < 2; ++i) {       // B: 8 KB = 8 issues, 2/wave
            const int t = w * 2 + i;
            const int row = t * 8 + lr8;
            gl16(W + (size_t)(n0r + row) * EE + kt + lc8 * 8,
                 (unsigned short*)Bs + t * 512);
        }
        __syncthreads();   // vmcnt drained by compiler before barrier

        #pragma unroll
        for (int ks = 0; ks < 2; ++ks) {
            short8 bfr[2], afr[4];
            #pragma unroll
            for (int nt = 0; nt < 2; ++nt)
                bfr[nt] = *(const short8*)((const char*)Bs + swz(wn * 32 + nt * 16 + c, ks * 4 + g));
            #pragma unroll
            for (int mt = 0; mt < 4; ++mt)
                afr[mt] = *(const short8*)((const char*)As + swz(wm * 64 + mt * 16 + c, ks * 4 + g));
            #pragma unroll
            for (int mt = 0; mt < 4; ++mt)
                #pragma unroll
                for (int nt = 0; nt < 2; ++nt)
                    acc[mt][nt] = __builtin_amdgcn_mfma_f32_16x16x32_bf16(
                        afr[mt], bfr[nt], acc[mt][nt], 0, 0, 0);
        }
    }
    __syncthreads();

    float bb[2];
    #pragma unroll
    for (int nt = 0; nt < 2; ++nt) bb[nt] = bias[n0r + wn * 32 + nt * 16 + c];

    const int bidx  = bm >> 11;
    const int sbase = bm & (SS - 1);

    if (proj < 2) {
        f32x4 vr[4][2];
        f32x4 ssp[4];
        #pragma unroll
        for (int mt = 0; mt < 4; ++mt) {
            #pragma unroll
            for (int nt = 0; nt < 2; ++nt)
                #pragma unroll
                for (int j = 0; j < 4; ++j)
                    vr[mt][nt][j] = acc[mt][nt][j] + bb[nt];
            #pragma unroll
            for (int j = 0; j < 4; ++j)
                ssp[mt][j] = vr[mt][0][j]*vr[mt][0][j] + vr[mt][1][j]*vr[mt][1][j];
            #pragma unroll
            for (int j = 0; j < 4; ++j) {
                float s = ssp[mt][j];
                #pragma unroll
                for (int msk = 1; msk < 16; msk <<= 1) s += __shfl_xor(s, msk);
                ssp[mt][j] = s;
            }
        }
        if (c == 0) {
            #pragma unroll
            for (int mt = 0; mt < 4; ++mt)
                #pragma unroll
                for (int j = 0; j < 4; ++j)
                    ssq[wn][wm * 64 + mt * 16 + g * 4 + j] = ssp[mt][j];
        }
        __syncthreads();
        unsigned short* dst = (proj == 0) ? qo : ko;
        const float fold = (proj == 0) ? 0.125f : 1.0f;
        #pragma unroll
        for (int mt = 0; mt < 4; ++mt) {
            #pragma unroll
            for (int j = 0; j < 4; ++j) {
                const int rloc = wm * 64 + mt * 16 + g * 4 + j;
                const float ss = ssq[0][rloc] + ssq[1][rloc];
                const float inv = fold / fmaxf(sqrtf(ss), 1e-6f);
                const size_t base =
                    ((size_t)(bidx * HH + h) * SS + sbase + rloc) * DD;
                #pragma unroll
                for (int nt = 0; nt < 2; ++nt)
                    dst[base + wn * 32 + nt * 16 + c] = f2bf(vr[mt][nt][j] * inv);
            }
        }
    } else {
        // V: +bias, transpose via LDS (reuse As as [128 s][64 d]), store [bh][d][s]
        #pragma unroll
        for (int mt = 0; mt < 4; ++mt)
            #pragma unroll
            for (int nt = 0; nt < 2; ++nt)
                #pragma unroll
                for (int j = 0; j < 4; ++j) {
                    const int row = wm * 64 + mt * 16 + g * 4 + j;
                    const int col = wn * 32 + nt * 16 + c;
                    As[row * 64 + col] = (short)f2bf(acc[mt][nt][j] + bb[nt]);
                }
        __syncthreads();
        const int d  = tid & 63;
        const int sb = (tid >> 6) * 32;
        unsigned short* dstp = vo + ((size_t)(bidx * HH + h) * DD + d) * SS + sbase + sb;
        #pragma unroll
        for (int grp = 0; grp < 4; ++grp) {
            unsigned int wds[4];
            #pragma unroll
            for (int e = 0; e < 4; ++e) {
                unsigned short u0 = (unsigned short)As[(sb + grp * 8 + 2 * e)     * 64 + d];
                unsigned short u1 = (unsigned short)As[(sb + grp * 8 + 2 * e + 1) * 64 + d];
                wds[e] = (unsigned int)u0 | ((unsigned int)u1 << 16);
            }
            int4 pk = make_int4((int)wds[0], (int)wds[1], (int)wds[2], (int)wds[3]);
            *(int4*)(dstp + grp * 8) = pk;
        }
    }
}

// ---------------------------------------------------------------------------
// Kernel 2: flash attention, bf16 MFMA. q,k [bh][s][d]; v transposed [bh][d][s].
// grid (SS/64, B*H), 128 thr = 2 waves; wave owns 32 q-rows (Mrep=2); KVBLK=64.
// No max-tracking (|score| <= 0.126 from l2-norm x SCALE). K/V via gl16 with
// pre-swizzled source; P per-wave in swizzled LDS.
// ---------------------------------------------------------------------------
__global__ __launch_bounds__(128) void attn_mfma_kernel(
    const unsigned short* __restrict__ q, const unsigned short* __restrict__ k,
    const unsigned short* __restrict__ vT, unsigned short* __restrict__ ctx)
{
    __shared__ short Ks[64 * 64];        // [key][d]  8 KB
    __shared__ short Vs[64 * 64];        // [d][key]  8 KB
    __shared__ short Ps[2 * 32 * 64];    // per-wave [qrow 32][key 64]  8 KB

    const int tid = threadIdx.x;
    const int bh  = blockIdx.y;
    const int w   = tid >> 6;
    const int l   = tid & 63;
    const int c   = l & 15;
    const int g   = l >> 4;
    const int lr8 = l >> 3;
    const int lc8 = (l & 7) ^ lr8;
    const int qr0 = blockIdx.x * 64 + w * 32;

    // Q A-frags in registers, reused across all KV tiles
    short8 aq[2][2];
    #pragma unroll
    for (int m = 0; m < 2; ++m) {
        const unsigned short* qg = q + ((size_t)bh * SS + qr0 + m * 16 + c) * DD;
        aq[m][0] = *(const short8*)(qg + g * 8);
        aq[m][1] = *(const short8*)(qg + 32 + g * 8);
    }

    short* Psw = Ps + w * (32 * 64);
    f32x4 o[2][4] = {};
    f32x4 lsum[2] = {};

    for (int s0 = 0; s0 < SS; s0 += 64) {
        __syncthreads();   // prev tile's K/V frag reads done
        #pragma unroll
        for (int i = 0; i < 4; ++i) {     // K: 8 issues, 4/wave
            const int t = w * 4 + i;
            gl16(k + ((size_t)bh * SS + s0 + t * 8 + lr8) * DD + lc8 * 8,
                 (unsigned short*)Ks + t * 512);
        }
        #pragma unroll
        for (int i = 0; i < 4; ++i) {     // V: 8 issues, 4/wave
            const int t = w * 4 + i;
            gl16(vT + ((size_t)bh * DD + t * 8 + lr8) * SS + s0 + lc8 * 8,
                 (unsigned short*)Vs + t * 512);
        }
        __syncthreads();

        // QK^T
        f32x4 sc[2][4] = {};
        #pragma unroll
        for (int ks = 0; ks < 2; ++ks)
            #pragma unroll
            for (int nt = 0; nt < 4; ++nt) {
                short8 kf = *(const short8*)((const char*)Ks + swz(nt * 16 + c, ks * 4 + g));
                #pragma unroll
                for (int m = 0; m < 2; ++m)
                    sc[m][nt] = __builtin_amdgcn_mfma_f32_16x16x32_bf16(
                        aq[m][ks], kf, sc[m][nt], 0, 0, 0);
            }

        // softmax numerators (no max subtraction; |sc| <= ~0.13)
        #pragma unroll
        for (int m = 0; m < 2; ++m) {
            f32x4 p[4];
            #pragma unroll
            for (int nt = 0; nt < 4; ++nt)
                #pragma unroll
                for (int j = 0; j < 4; ++j)
                    p[nt][j] = __expf(sc[m][nt][j]);
            #pragma unroll
            for (int j = 0; j < 4; ++j) {
                float r = p[0][j] + p[1][j] + p[2][j] + p[3][j];
                #pragma unroll
                for (int msk = 1; msk < 16; msk <<= 1) r += __shfl_xor(r, msk);
                lsum[m][j] += r;
            }
            #pragma unroll
            for (int nt = 0; nt < 4; ++nt)
                #pragma unroll
                for (int j = 0; j < 4; ++j) {
                    const int row = m * 16 + g * 4 + j;
                    const int ch  = (nt * 2 + (c >> 3)) ^ (row & 7);
                    Psw[row * 64 + (ch << 3) + (c & 7)] = (short)f2bf(p[nt][j]);
                }
        }

        // PV (P write->read same wave: compiler inserts lgkmcnt wait)
        #pragma unroll
        for (int ks = 0; ks < 2; ++ks) {
            short8 pa[2];
            #pragma unroll
            for (int m = 0; m < 2; ++m)
                pa[m] = *(const short8*)((const char*)Psw + swz(m * 16 + c, ks * 4 + g));
            #pragma unroll
            for (int dt = 0; dt < 4; ++dt) {
                short8 vf = *(const short8*)((const char*)Vs + swz(dt * 16 + c, ks * 4 + g));
                #pragma unroll
                for (int m = 0; m < 2; ++m)
                    o[m][dt] = __builtin_amdgcn_mfma_f32_16x16x32_bf16(
                        pa[m], vf, o[m][dt], 0, 0, 0);
            }
        }
    }

    // epilogue: divide by denom, store ctx bf16 [b][s][e]
    const int bidx = bh / HH, h = bh % HH;
    #pragma unroll
    for (int m = 0; m < 2; ++m)
        #pragma unroll
        for (int j = 0; j < 4; ++j) {
            const float inv = 1.0f / lsum[m][j];
            const int sg = qr0 + m * 16 + g * 4 + j;
            unsigned short* op = ctx + ((size_t)bidx * SS + sg) * EE + h * DD + c;
            #pragma unroll
            for (int dt = 0; dt < 4; ++dt)
                op[dt * 16] = f2bf(o[m][dt][j] * inv);
        }
}

// ---------------------------------------------------------------------------
// Kernel 3: output projection, MFMA.  out = ctx(bf16) @ Wo.T + bo  (fp32 out)
// grid (MM/128, EE/64), same structure as kernel 1.
// ---------------------------------------------------------------------------
__global__ __launch_bounds__(256) void out_mfma_kernel(
    const unsigned short* __restrict__ A, const unsigned short* __restrict__ W,
    const float* __restrict__ bias, float* __restrict__ out)
{
    __shared__ short As[128 * 64];
    __shared__ short Bs[64 * 64];

    const int tid = threadIdx.x;
    const int bm  = blockIdx.x * 128;
    const int n0  = blockIdx.y * 64;

    const int w  = tid >> 6;
    const int l  = tid & 63;
    const int c  = l & 15;
    const int g  = l >> 4;
    const int wm = w >> 1;
    const int wn = w & 1;
    const int lr8 = l >> 3;
    const int lc8 = (l & 7) ^ lr8;

    f32x4 acc[4][2] = {};

    for (int kt = 0; kt < EE; kt += 64) {
        __syncthreads();
        #pragma unroll
        for (int i = 0; i < 4; ++i) {
            const int t = w * 4 + i;
            const int row = t * 8 + lr8;
            gl16(A + (size_t)(bm + row) * EE + kt + lc8 * 8,
                 (unsigned short*)As + t * 512);
        }
        #pragma unroll
        for (int i = 0; i < 2; ++i) {
            const int t = w * 2 + i;
            const int row = t * 8 + lr8;
            gl16(W + (size_t)(n0 + row) * EE + kt + lc8 * 8,
                 (unsigned short*)Bs + t * 512);
        }
        __syncthreads();

        #pragma unroll
        for (int ks = 0; ks < 2; ++ks) {
            short8 bfr[2], afr[4];
            #pragma unroll
            for (int nt = 0; nt < 2; ++nt)
                bfr[nt] = *(const short8*)((const char*)Bs + swz(wn * 32 + nt * 16 + c, ks * 4 + g));
            #pragma unroll
            for (int mt = 0; mt < 4; ++mt)
                afr[mt] = *(const short8*)((const char*)As + swz(wm * 64 + mt * 16 + c, ks * 4 + g));
            #pragma unroll
            for (int mt = 0; mt < 4; ++mt)
                #pragma unroll
                for (int nt = 0; nt < 2; ++nt)
                    acc[mt][nt] = __builtin_amdgcn_mfma_f32_16x16x32_bf16(
                        afr[mt], bfr[nt], acc[mt][nt], 0, 0, 0);
        }
    }

    float bb[2];
    #pragma unroll
    for (int nt = 0; nt < 2; ++nt) bb[nt] = bias[n0 + wn * 32 + nt * 16 + c];

    #pragma unroll
    for (int mt = 0; mt < 4; ++mt)
        #pragma unroll
        for (int j = 0; j < 4; ++j) {
            const int row = bm + wm * 64 + mt * 16 + g * 4 + j;
            float* op = out + (size_t)row * EE + n0 + wn * 32 + c;
            #pragma unroll
            for (int nt = 0; nt < 2; ++nt)
                op[nt * 16] = acc[mt][nt][j] + bb[nt];
        }
}

// ---------------------------------------------------------------------------
extern "C" void kernel_launch(void* const* d_in, const int* in_sizes, int n_in,
                              void* d_out, int out_size, void* d_ws, size_t ws_size,
                              hipStream_t stream)
{
    const float* query = (const float*)d_in[0];
    const float* key   = (const float*)d_in[1];
    const float* value = (const float*)d_in[2];
    const float* Wq = (const float*)d_in[3];
    const float* bq = (const float*)d_in[4];
    const float* Wk = (const float*)d_in[5];
    const float* bk = (const float*)d_in[6];
    const float* Wv = (const float*)d_in[7];
    const float* bv = (const float*)d_in[8];
    const float* Wo = (const float*)d_in[9];
    const float* bo = (const float*)d_in[10];
    float* out = (float*)d_out;

    // ws: xqc/xkc/xvc (bf16 inputs), q/k/vT (bf16 heads), W's bf16.
    // ctx aliases xqc (qkv consumed it before attn writes; stream-ordered).
    unsigned short* xqc  = (unsigned short*)d_ws;
    unsigned short* xkc  = xqc  + NT;
    unsigned short* xvc  = xkc  + NT;
    unsigned short* qws  = xvc  + NT;
    unsigned short* kws  = qws  + NT;
    unsigned short* vtws = kws  + NT;
    unsigned short* wqc  = vtws + NT;
    unsigned short* wkc  = wqc  + NW;
    unsigned short* wvc  = wkc  + NW;
    unsigned short* woc  = wvc  + NW;
    unsigned short* ctx  = xqc;          // alias

    cvt_x_kernel<<<dim3(NT / 4 / 256, 3), 256, 0, stream>>>(
        query, key, value, xqc, xkc, xvc);
    cvt_w_kernel<<<dim3(NW / 4 / 256, 4), 256, 0, stream>>>(
        Wq, Wk, Wv, Wo, wqc, wkc, wvc, woc);
    qkv_mfma_kernel<<<dim3(MM / 128, 36), 256, 0, stream>>>(
        xqc, xkc, xvc, wqc, bq, wkc, bk, wvc, bv, qws, kws, vtws);
    attn_mfma_kernel<<<dim3(SS / 64, BB * HH), 128, 0, stream>>>(
        qws, kws, vtws, ctx);
    out_mfma_kernel<<<dim3(MM / 128, EE / 64), 256, 0, stream>>>(
        ctx, woc, bo, out);
}

// Round 7
// 234.595 us; speedup vs baseline: 3.6857x; 1.0025x over previous
//
#include <hip/hip_runtime.h>
#include <hip/hip_bf16.h>

#define EE 768
#define HH 12
#define DD 64
#define BB 2
#define SS 2048
#define MM (BB*SS)          // 4096
#define NT (MM*EE)          // 3,145,728 elements (also B*H*S*D)
#define NW (EE*EE)          // 589,824

typedef short short8 __attribute__((ext_vector_type(8)));   // 8 bf16 = 4 VGPR (MFMA A/B frag)
typedef float f32x4 __attribute__((ext_vector_type(4)));    // MFMA C/D frag

static __device__ __forceinline__ unsigned short f2bf(float f) {
    unsigned int u = __float_as_uint(f);
    u += 0x7fffu + ((u >> 16) & 1u);      // round-to-nearest-even
    return (unsigned short)(u >> 16);
}

// async 16B global->LDS. LDS dest = wave-uniform base + lane*16 (HW rule).
static __device__ __forceinline__ void gl16(const void* g, void* l) {
    __builtin_amdgcn_global_load_lds(
        (const __attribute__((address_space(1))) unsigned int*)g,
        (__attribute__((address_space(3))) unsigned int*)l, 16, 0, 0);
}

// Swizzled byte offset in a [R][64] bf16 LDS tile (128B rows, 8x16B chunks).
// Staging pre-swizzles the per-lane GLOBAL source chunk ((l&7)^(l>>3)) so the
// linear gl16 dest holds swizzled content; reads via swz() are conflict-free
// (rule #21: both-sides-or-neither).
static __device__ __forceinline__ int swz(int row, int chunk) {
    return row * 128 + ((chunk ^ (row & 7)) << 4);
}

// ---------------------------------------------------------------------------
// fp32 -> bf16 pre-convert, all 7 tensors in one launch (memory-bound).
// ---------------------------------------------------------------------------
__global__ __launch_bounds__(256) void cvt_all_kernel(
    const float* __restrict__ xq, const float* __restrict__ xk, const float* __restrict__ xv,
    const float* __restrict__ wq, const float* __restrict__ wk,
    const float* __restrict__ wv, const float* __restrict__ wo,
    unsigned short* __restrict__ oq, unsigned short* __restrict__ ok, unsigned short* __restrict__ ov,
    unsigned short* __restrict__ owq, unsigned short* __restrict__ owk,
    unsigned short* __restrict__ owv, unsigned short* __restrict__ owo)
{
    const int XQ = NT / 4;   // quads per x tensor
    const int WQ = NW / 4;   // quads per W tensor
    const int idx = blockIdx.x * 256 + threadIdx.x;
    const float* s;
    unsigned short* d;
    int off;
    if (idx < 3 * XQ) {
        const int r = idx / XQ;
        off = idx - r * XQ;
        s = (r == 0) ? xq : (r == 1) ? xk : xv;
        d = (r == 0) ? oq : (r == 1) ? ok : ov;
    } else {
        const int j = idx - 3 * XQ;
        const int r = j / WQ;
        off = j - r * WQ;
        s = (r == 0) ? wq : (r == 1) ? wk : (r == 2) ? wv : wo;
        d = (r == 0) ? owq : (r == 1) ? owk : (r == 2) ? owv : owo;
    }
    float4 f = ((const float4*)s)[off];
    ushort4 u;
    u.x = f2bf(f.x); u.y = f2bf(f.y); u.z = f2bf(f.z); u.w = f2bf(f.w);
    ((ushort4*)d)[off] = u;
}

// stage one 128x64 A-tile + 64x64 B-tile K-step into LDS (per-wave slice)
static __device__ __forceinline__ void stage_ab(
    const unsigned short* __restrict__ x, const unsigned short* __restrict__ W,
    int bm, int n0, int kt, short* Abuf, short* Bbuf, int w, int lr8, int lc8)
{
    #pragma unroll
    for (int i = 0; i < 4; ++i) {       // A: 16 issues, 4/wave
        const int t = w * 4 + i;
        gl16(x + (size_t)(bm + t * 8 + lr8) * EE + kt + lc8 * 8,
             (unsigned short*)Abuf + t * 512);
    }
    #pragma unroll
    for (int i = 0; i < 2; ++i) {       // B: 8 issues, 2/wave
        const int t = w * 2 + i;
        gl16(W + (size_t)(n0 + t * 8 + lr8) * EE + kt + lc8 * 8,
             (unsigned short*)Bbuf + t * 512);
    }
}

// ---------------------------------------------------------------------------
// Kernel 1: QKV projection, MFMA, 2-phase double-buffered staging (T3-min).
// grid (MM/128, 36): by 0-11 q(head), 12-23 k, 24-35 v.
// BM=128 BN=64 BK=64, 256 thr = 4 waves (2Mx2N), per-wave 64x32.
// Epilogue: +bias; q/k l2-norm over head (SCALE folded into q) -> bf16 [bh][s][d];
// v -> transposed bf16 [bh][d][s] via LDS.
// ---------------------------------------------------------------------------
__global__ __launch_bounds__(256) void qkv_mfma_kernel(
    const unsigned short* __restrict__ xq, const unsigned short* __restrict__ xk,
    const unsigned short* __restrict__ xv,
    const unsigned short* __restrict__ Wq, const float* __restrict__ bq,
    const unsigned short* __restrict__ Wk, const float* __restrict__ bk,
    const unsigned short* __restrict__ Wv, const float* __restrict__ bv,
    unsigned short* __restrict__ qo, unsigned short* __restrict__ ko,
    unsigned short* __restrict__ vo)
{
    __shared__ short As[2][128 * 64];   // 32 KB
    __shared__ short Bs[2][64 * 64];    // 16 KB
    __shared__ float ssq[2][128];       //  1 KB

    const int tid = threadIdx.x;
    const int bm  = blockIdx.x * 128;
    const int by  = blockIdx.y;
    const int proj = by / 12;
    const int h    = by % 12;
    const int n0r  = h * 64;

    const unsigned short* x = (proj == 0) ? xq : (proj == 1) ? xk : xv;
    const unsigned short* W = (proj == 0) ? Wq : (proj == 1) ? Wk : Wv;
    const float* bias       = (proj == 0) ? bq : (proj == 1) ? bk : bv;

    const int w  = tid >> 6;
    const int l  = tid & 63;
    const int c  = l & 15;
    const int g  = l >> 4;
    const int wm = w >> 1;
    const int wn = w & 1;
    const int lr8 = l >> 3;                 // 0..7: row-in-issue
    const int lc8 = (l & 7) ^ lr8;          // pre-swizzled source chunk

    f32x4 acc[4][2] = {};

    stage_ab(x, W, bm, n0r, 0, As[0], Bs[0], w, lr8, lc8);
    __syncthreads();                         // drain tile-0 loads

    for (int it = 0; it < EE / 64; ++it) {
        const int cur = it & 1;
        if (it + 1 < EE / 64)                // prefetch next K-step (async)
            stage_ab(x, W, bm, n0r, (it + 1) * 64, As[cur ^ 1], Bs[cur ^ 1], w, lr8, lc8);

        #pragma unroll
        for (int ks = 0; ks < 2; ++ks) {
            short8 bfr[2], afr[4];
            #pragma unroll
            for (int nt = 0; nt < 2; ++nt)
                bfr[nt] = *(const short8*)((const char*)Bs[cur] + swz(wn * 32 + nt * 16 + c, ks * 4 + g));
            #pragma unroll
            for (int mt = 0; mt < 4; ++mt)
                afr[mt] = *(const short8*)((const char*)As[cur] + swz(wm * 64 + mt * 16 + c, ks * 4 + g));
            #pragma unroll
            for (int mt = 0; mt < 4; ++mt)
                #pragma unroll
                for (int nt = 0; nt < 2; ++nt)
                    acc[mt][nt] = __builtin_amdgcn_mfma_f32_16x16x32_bf16(
                        afr[mt], bfr[nt], acc[mt][nt], 0, 0, 0);
        }
        __syncthreads();   // one barrier/tile: drains prefetch AFTER compute
    }

    float bb[2];
    #pragma unroll
    for (int nt = 0; nt < 2; ++nt) bb[nt] = bias[n0r + wn * 32 + nt * 16 + c];

    const int bidx  = bm >> 11;
    const int sbase = bm & (SS - 1);

    if (proj < 2) {
        f32x4 vr[4][2];
        f32x4 ssp[4];
        #pragma unroll
        for (int mt = 0; mt < 4; ++mt) {
            #pragma unroll
            for (int nt = 0; nt < 2; ++nt)
                #pragma unroll
                for (int j = 0; j < 4; ++j)
                    vr[mt][nt][j] = acc[mt][nt][j] + bb[nt];
            #pragma unroll
            for (int j = 0; j < 4; ++j)
                ssp[mt][j] = vr[mt][0][j]*vr[mt][0][j] + vr[mt][1][j]*vr[mt][1][j];
            #pragma unroll
            for (int j = 0; j < 4; ++j) {
                float s = ssp[mt][j];
                #pragma unroll
                for (int msk = 1; msk < 16; msk <<= 1) s += __shfl_xor(s, msk);
                ssp[mt][j] = s;
            }
        }
        if (c == 0) {
            #pragma unroll
            for (int mt = 0; mt < 4; ++mt)
                #pragma unroll
                for (int j = 0; j < 4; ++j)
                    ssq[wn][wm * 64 + mt * 16 + g * 4 + j] = ssp[mt][j];
        }
        __syncthreads();
        unsigned short* dst = (proj == 0) ? qo : ko;
        const float fold = (proj == 0) ? 0.125f : 1.0f;
        #pragma unroll
        for (int mt = 0; mt < 4; ++mt) {
            #pragma unroll
            for (int j = 0; j < 4; ++j) {
                const int rloc = wm * 64 + mt * 16 + g * 4 + j;
                const float ss = ssq[0][rloc] + ssq[1][rloc];
                const float inv = fold / fmaxf(sqrtf(ss), 1e-6f);
                const size_t base =
                    ((size_t)(bidx * HH + h) * SS + sbase + rloc) * DD;
                #pragma unroll
                for (int nt = 0; nt < 2; ++nt)
                    dst[base + wn * 32 + nt * 16 + c] = f2bf(vr[mt][nt][j] * inv);
            }
        }
    } else {
        // V: +bias, transpose via LDS (reuse As[0] as [128 s][64 d]), store [bh][d][s]
        short* T = As[0];
        #pragma unroll
        for (int mt = 0; mt < 4; ++mt)
            #pragma unroll
            for (int nt = 0; nt < 2; ++nt)
                #pragma unroll
                for (int j = 0; j < 4; ++j) {
                    const int row = wm * 64 + mt * 16 + g * 4 + j;
                    const int col = wn * 32 + nt * 16 + c;
                    T[row * 64 + col] = (short)f2bf(acc[mt][nt][j] + bb[nt]);
                }
        __syncthreads();
        const int d  = tid & 63;
        const int sb = (tid >> 6) * 32;
        unsigned short* dstp = vo + ((size_t)(bidx * HH + h) * DD + d) * SS + sbase + sb;
        #pragma unroll
        for (int grp = 0; grp < 4; ++grp) {
            unsigned int wds[4];
            #pragma unroll
            for (int e = 0; e < 4; ++e) {
                unsigned short u0 = (unsigned short)T[(sb + grp * 8 + 2 * e)     * 64 + d];
                unsigned short u1 = (unsigned short)T[(sb + grp * 8 + 2 * e + 1) * 64 + d];
                wds[e] = (unsigned int)u0 | ((unsigned int)u1 << 16);
            }
            int4 pk = make_int4((int)wds[0], (int)wds[1], (int)wds[2], (int)wds[3]);
            *(int4*)(dstp + grp * 8) = pk;
        }
    }
}

// stage one 64x64 K-tile + 64x64 V-tile into LDS (per-wave slice, 2 waves)
static __device__ __forceinline__ void stage_kv(
    const unsigned short* __restrict__ kbase, const unsigned short* __restrict__ vbase,
    int s0, short* Kbuf, short* Vbuf, int w, int lr8, int lc8)
{
    #pragma unroll
    for (int i = 0; i < 4; ++i) {     // K: 8 issues, 4/wave
        const int t = w * 4 + i;
        gl16(kbase + (size_t)(s0 + t * 8 + lr8) * DD + lc8 * 8,
             (unsigned short*)Kbuf + t * 512);
    }
    #pragma unroll
    for (int i = 0; i < 4; ++i) {     // V: 8 issues, 4/wave
        const int t = w * 4 + i;
        gl16(vbase + (size_t)(t * 8 + lr8) * SS + s0 + lc8 * 8,
             (unsigned short*)Vbuf + t * 512);
    }
}

// ---------------------------------------------------------------------------
// Kernel 2: flash attention, bf16 MFMA, 2-phase double-buffered K/V staging.
// q,k [bh][s][d]; v transposed [bh][d][s]. grid (SS/64, B*H), 128 thr = 2 waves;
// wave owns 32 q-rows (Mrep=2); KVBLK=64. No max-tracking (|score| <= 0.126).
// One __syncthreads per KV tile: prefetch issued BEFORE compute, drained after.
// ---------------------------------------------------------------------------
__global__ __launch_bounds__(128) void attn_mfma_kernel(
    const unsigned short* __restrict__ q, const unsigned short* __restrict__ k,
    const unsigned short* __restrict__ vT, unsigned short* __restrict__ ctx)
{
    __shared__ short Ks[2][64 * 64];     // 16 KB
    __shared__ short Vs[2][64 * 64];     // 16 KB
    __shared__ short Ps[2 * 32 * 64];    //  8 KB  per-wave [qrow 32][key 64]

    const int tid = threadIdx.x;
    const int bh  = blockIdx.y;
    const int w   = tid >> 6;
    const int l   = tid & 63;
    const int c   = l & 15;
    const int g   = l >> 4;
    const int lr8 = l >> 3;
    const int lc8 = (l & 7) ^ lr8;
    const int qr0 = blockIdx.x * 64 + w * 32;

    const unsigned short* kbase = k  + (size_t)bh * SS * DD;
    const unsigned short* vbase = vT + (size_t)bh * DD * SS;

    // Q A-frags in registers, reused across all KV tiles
    short8 aq[2][2];
    #pragma unroll
    for (int m = 0; m < 2; ++m) {
        const unsigned short* qg = q + ((size_t)bh * SS + qr0 + m * 16 + c) * DD;
        aq[m][0] = *(const short8*)(qg + g * 8);
        aq[m][1] = *(const short8*)(qg + 32 + g * 8);
    }

    short* Psw = Ps + w * (32 * 64);
    f32x4 o[2][4] = {};
    f32x4 lsum[2] = {};

    stage_kv(kbase, vbase, 0, Ks[0], Vs[0], w, lr8, lc8);
    __syncthreads();                         // drain tile-0 loads

    for (int t = 0; t < SS / 64; ++t) {
        const int cur = t & 1;
        if (t + 1 < SS / 64)                 // prefetch next KV tile (async)
            stage_kv(kbase, vbase, (t + 1) * 64, Ks[cur ^ 1], Vs[cur ^ 1], w, lr8, lc8);

        // QK^T
        f32x4 sc[2][4] = {};
        #pragma unroll
        for (int ks = 0; ks < 2; ++ks)
            #pragma unroll
            for (int nt = 0; nt < 4; ++nt) {
                short8 kf = *(const short8*)((const char*)Ks[cur] + swz(nt * 16 + c, ks * 4 + g));
                #pragma unroll
                for (int m = 0; m < 2; ++m)
                    sc[m][nt] = __builtin_amdgcn_mfma_f32_16x16x32_bf16(
                        aq[m][ks], kf, sc[m][nt], 0, 0, 0);
            }

        // softmax numerators (no max subtraction; |sc| <= ~0.13)
        #pragma unroll
        for (int m = 0; m < 2; ++m) {
            f32x4 p[4];
            #pragma unroll
            for (int nt = 0; nt < 4; ++nt)
                #pragma unroll
                for (int j = 0; j < 4; ++j)
                    p[nt][j] = __expf(sc[m][nt][j]);
            #pragma unroll
            for (int j = 0; j < 4; ++j) {
                float r = p[0][j] + p[1][j] + p[2][j] + p[3][j];
                #pragma unroll
                for (int msk = 1; msk < 16; msk <<= 1) r += __shfl_xor(r, msk);
                lsum[m][j] += r;
            }
            #pragma unroll
            for (int nt = 0; nt < 4; ++nt)
                #pragma unroll
                for (int j = 0; j < 4; ++j) {
                    const int row = m * 16 + g * 4 + j;
                    const int ch  = (nt * 2 + (c >> 3)) ^ (row & 7);
                    Psw[row * 64 + (ch << 3) + (c & 7)] = (short)f2bf(p[nt][j]);
                }
        }

        // PV (P write->read same wave: lgkmcnt ordering)
        #pragma unroll
        for (int ks = 0; ks < 2; ++ks) {
            short8 pa[2];
            #pragma unroll
            for (int m = 0; m < 2; ++m)
                pa[m] = *(const short8*)((const char*)Psw + swz(m * 16 + c, ks * 4 + g));
            #pragma unroll
            for (int dt = 0; dt < 4; ++dt) {
                short8 vf = *(const short8*)((const char*)Vs[cur] + swz(dt * 16 + c, ks * 4 + g));
                #pragma unroll
                for (int m = 0; m < 2; ++m)
                    o[m][dt] = __builtin_amdgcn_mfma_f32_16x16x32_bf16(
                        pa[m], vf, o[m][dt], 0, 0, 0);
            }
        }
        __syncthreads();   // one barrier/tile: drains prefetch AFTER compute
    }

    // epilogue: divide by denom, store ctx bf16 [b][s][e]
    const int bidx = bh / HH, h = bh % HH;
    #pragma unroll
    for (int m = 0; m < 2; ++m)
        #pragma unroll
        for (int j = 0; j < 4; ++j) {
            const float inv = 1.0f / lsum[m][j];
            const int sg = qr0 + m * 16 + g * 4 + j;
            unsigned short* op = ctx + ((size_t)bidx * SS + sg) * EE + h * DD + c;
            #pragma unroll
            for (int dt = 0; dt < 4; ++dt)
                op[dt * 16] = f2bf(o[m][dt][j] * inv);
        }
}

// ---------------------------------------------------------------------------
// Kernel 3: output projection, MFMA, 2-phase double-buffered staging.
// out = ctx(bf16) @ Wo.T + bo (fp32 out). grid (MM/128, EE/64).
// ---------------------------------------------------------------------------
__global__ __launch_bounds__(256) void out_mfma_kernel(
    const unsigned short* __restrict__ A, const unsigned short* __restrict__ W,
    const float* __restrict__ bias, float* __restrict__ out)
{
    __shared__ short As[2][128 * 64];
    __shared__ short Bs[2][64 * 64];

    const int tid = threadIdx.x;
    const int bm  = blockIdx.x * 128;
    const int n0  = blockIdx.y * 64;

    const int w  = tid >> 6;
    const int l  = tid & 63;
    const int c  = l & 15;
    const int g  = l >> 4;
    const int wm = w >> 1;
    const int wn = w & 1;
    const int lr8 = l >> 3;
    const int lc8 = (l & 7) ^ lr8;

    f32x4 acc[4][2] = {};

    stage_ab(A, W, bm, n0, 0, As[0], Bs[0], w, lr8, lc8);
    __syncthreads();

    for (int it = 0; it < EE / 64; ++it) {
        const int cur = it & 1;
        if (it + 1 < EE / 64)
            stage_ab(A, W, bm, n0, (it + 1) * 64, As[cur ^ 1], Bs[cur ^ 1], w, lr8, lc8);

        #pragma unroll
        for (int ks = 0; ks < 2; ++ks) {
            short8 bfr[2], afr[4];
            #pragma unroll
            for (int nt = 0; nt < 2; ++nt)
                bfr[nt] = *(const short8*)((const char*)Bs[cur] + swz(wn * 32 + nt * 16 + c, ks * 4 + g));
            #pragma unroll
            for (int mt = 0; mt < 4; ++mt)
                afr[mt] = *(const short8*)((const char*)As[cur] + swz(wm * 64 + mt * 16 + c, ks * 4 + g));
            #pragma unroll
            for (int mt = 0; mt < 4; ++mt)
                #pragma unroll
                for (int nt = 0; nt < 2; ++nt)
                    acc[mt][nt] = __builtin_amdgcn_mfma_f32_16x16x32_bf16(
                        afr[mt], bfr[nt], acc[mt][nt], 0, 0, 0);
        }
        __syncthreads();
    }

    float bb[2];
    #pragma unroll
    for (int nt = 0; nt < 2; ++nt) bb[nt] = bias[n0 + wn * 32 + nt * 16 + c];

    #pragma unroll
    for (int mt = 0; mt < 4; ++mt)
        #pragma unroll
        for (int j = 0; j < 4; ++j) {
            const int row = bm + wm * 64 + mt * 16 + g * 4 + j;
            float* op = out + (size_t)row * EE + n0 + wn * 32 + c;
            #pragma unroll
            for (int nt = 0; nt < 2; ++nt)
                op[nt * 16] = acc[mt][nt][j] + bb[nt];
        }
}

// ---------------------------------------------------------------------------
extern "C" void kernel_launch(void* const* d_in, const int* in_sizes, int n_in,
                              void* d_out, int out_size, void* d_ws, size_t ws_size,
                              hipStream_t stream)
{
    const float* query = (const float*)d_in[0];
    const float* key   = (const float*)d_in[1];
    const float* value = (const float*)d_in[2];
    const float* Wq = (const float*)d_in[3];
    const float* bq = (const float*)d_in[4];
    const float* Wk = (const float*)d_in[5];
    const float* bk = (const float*)d_in[6];
    const float* Wv = (const float*)d_in[7];
    const float* bv = (const float*)d_in[8];
    const float* Wo = (const float*)d_in[9];
    const float* bo = (const float*)d_in[10];
    float* out = (float*)d_out;

    // ws: xqc/xkc/xvc (bf16 inputs), q/k/vT (bf16 heads), W's bf16.
    // ctx aliases xqc (qkv consumed it before attn writes; stream-ordered).
    unsigned short* xqc  = (unsigned short*)d_ws;
    unsigned short* xkc  = xqc  + NT;
    unsigned short* xvc  = xkc  + NT;
    unsigned short* qws  = xvc  + NT;
    unsigned short* kws  = qws  + NT;
    unsigned short* vtws = kws  + NT;
    unsigned short* wqc  = vtws + NT;
    unsigned short* wkc  = wqc  + NW;
    unsigned short* wvc  = wkc  + NW;
    unsigned short* woc  = wvc  + NW;
    unsigned short* ctx  = xqc;          // alias

    const int cvt_blocks = (3 * (NT / 4) + 4 * (NW / 4)) / 256;   // 11520
    cvt_all_kernel<<<dim3(cvt_blocks), 256, 0, stream>>>(
        query, key, value, Wq, Wk, Wv, Wo,
        xqc, xkc, xvc, wqc, wkc, wvc, woc);
    qkv_mfma_kernel<<<dim3(MM / 128, 36), 256, 0, stream>>>(
        xqc, xkc, xvc, wqc, bq, wkc, bk, wvc, bv, qws, kws, vtws);
    attn_mfma_kernel<<<dim3(SS / 64, BB * HH), 128, 0, stream>>>(
        qws, kws, vtws, ctx);
    out_mfma_kernel<<<dim3(MM / 128, EE / 64), 256, 0, stream>>>(
        ctx, woc, bo, out);
}

// Round 9
// 202.455 us; speedup vs baseline: 4.2708x; 1.1588x over previous
//
#include <hip/hip_runtime.h>
#include <hip/hip_bf16.h>

#define EE 768
#define HH 12
#define DD 64
#define BB 2
#define SS 2048
#define MM (BB*SS)          // 4096
#define NT (MM*EE)          // 3,145,728 elements (also B*H*S*D)
#define NW (EE*EE)          // 589,824

typedef short short8 __attribute__((ext_vector_type(8)));   // 8 bf16 = 4 VGPR (MFMA A/B frag)
typedef float f32x4 __attribute__((ext_vector_type(4)));    // MFMA C/D frag

static __device__ __forceinline__ unsigned short f2bf(float f) {
    unsigned int u = __float_as_uint(f);
    u += 0x7fffu + ((u >> 16) & 1u);      // round-to-nearest-even
    return (unsigned short)(u >> 16);
}

// async 16B global->LDS. LDS dest = wave-uniform base + lane*16 (HW rule).
static __device__ __forceinline__ void gl16(const void* g, void* l) {
    __builtin_amdgcn_global_load_lds(
        (const __attribute__((address_space(1))) unsigned int*)g,
        (__attribute__((address_space(3))) unsigned int*)l, 16, 0, 0);
}

// Swizzled byte offset in a [R][64] bf16 LDS tile (128B rows, 8x16B chunks).
// Staging pre-swizzles the per-lane GLOBAL source chunk ((l&7)^(l>>3)) so the
// linear gl16 dest holds swizzled content; reads via swz() are conflict-free
// (rule #21: both-sides-or-neither).
static __device__ __forceinline__ int swz(int row, int chunk) {
    return row * 128 + ((chunk ^ (row & 7)) << 4);
}

// ---------------------------------------------------------------------------
// fp32 -> bf16 pre-convert, all 7 tensors in one launch (memory-bound).
// ---------------------------------------------------------------------------
__global__ __launch_bounds__(256) void cvt_all_kernel(
    const float* __restrict__ xq, const float* __restrict__ xk, const float* __restrict__ xv,
    const float* __restrict__ wq, const float* __restrict__ wk,
    const float* __restrict__ wv, const float* __restrict__ wo,
    unsigned short* __restrict__ oq, unsigned short* __restrict__ ok, unsigned short* __restrict__ ov,
    unsigned short* __restrict__ owq, unsigned short* __restrict__ owk,
    unsigned short* __restrict__ owv, unsigned short* __restrict__ owo)
{
    const int XQ = NT / 4;   // quads per x tensor
    const int WQ = NW / 4;   // quads per W tensor
    const int idx = blockIdx.x * 256 + threadIdx.x;
    const float* s;
    unsigned short* d;
    int off;
    if (idx < 3 * XQ) {
        const int r = idx / XQ;
        off = idx - r * XQ;
        s = (r == 0) ? xq : (r == 1) ? xk : xv;
        d = (r == 0) ? oq : (r == 1) ? ok : ov;
    } else {
        const int j = idx - 3 * XQ;
        const int r = j / WQ;
        off = j - r * WQ;
        s = (r == 0) ? wq : (r == 1) ? wk : (r == 2) ? wv : wo;
        d = (r == 0) ? owq : (r == 1) ? owk : (r == 2) ? owv : owo;
    }
    float4 f = ((const float4*)s)[off];
    ushort4 u;
    u.x = f2bf(f.x); u.y = f2bf(f.y); u.z = f2bf(f.z); u.w = f2bf(f.w);
    ((ushort4*)d)[off] = u;
}

// ---------------------------------------------------------------------------
// Kernel 1: QKV projection, MFMA, single-buffered gl16 staging (round-5 form:
// measured best occupancy for this thin GEMM; dbuf regressed it, R7).
// grid (MM/128, 36): by 0-11 q(head), 12-23 k, 24-35 v.
// BM=128 BN=64 BK=64, 256 thr = 4 waves (2Mx2N), per-wave 64x32.
// Epilogue: +bias; q/k l2-norm over head; q additionally folds SCALE*log2e so
// attention can use exp2 directly. v -> transposed bf16 [bh][d][s] via LDS.
// ---------------------------------------------------------------------------
__global__ __launch_bounds__(256) void qkv_mfma_kernel(
    const unsigned short* __restrict__ xq, const unsigned short* __restrict__ xk,
    const unsigned short* __restrict__ xv,
    const unsigned short* __restrict__ Wq, const float* __restrict__ bq,
    const unsigned short* __restrict__ Wk, const float* __restrict__ bk,
    const unsigned short* __restrict__ Wv, const float* __restrict__ bv,
    unsigned short* __restrict__ qo, unsigned short* __restrict__ ko,
    unsigned short* __restrict__ vo)
{
    __shared__ short As[128 * 64];   // 16 KB
    __shared__ short Bs[64 * 64];    //  8 KB
    __shared__ float ssq[2][128];    //  1 KB

    const int tid = threadIdx.x;
    const int bm  = blockIdx.x * 128;
    const int by  = blockIdx.y;
    const int proj = by / 12;
    const int h    = by % 12;
    const int n0r  = h * 64;

    const unsigned short* x = (proj == 0) ? xq : (proj == 1) ? xk : xv;
    const unsigned short* W = (proj == 0) ? Wq : (proj == 1) ? Wk : Wv;
    const float* bias       = (proj == 0) ? bq : (proj == 1) ? bk : bv;

    const int w  = tid >> 6;
    const int l  = tid & 63;
    const int c  = l & 15;
    const int g  = l >> 4;
    const int wm = w >> 1;
    const int wn = w & 1;
    const int lr8 = l >> 3;                 // 0..7: row-in-issue
    const int lc8 = (l & 7) ^ lr8;          // pre-swizzled source chunk

    f32x4 acc[4][2] = {};

    for (int kt = 0; kt < EE; kt += 64) {
        __syncthreads();   // prev compute done before overwrite
        #pragma unroll
        for (int i = 0; i < 4; ++i) {       // A: 16 issues, 4/wave
            const int t = w * 4 + i;
            gl16(x + (size_t)(bm + t * 8 + lr8) * EE + kt + lc8 * 8,
                 (unsigned short*)As + t * 512);
        }
        #pragma unroll
        for (int i = 0; i < 2; ++i) {       // B: 8 issues, 2/wave
            const int t = w * 2 + i;
            gl16(W + (size_t)(n0r + t * 8 + lr8) * EE + kt + lc8 * 8,
                 (unsigned short*)Bs + t * 512);
        }
        __syncthreads();   // vmcnt drained by compiler before barrier

        #pragma unroll
        for (int ks = 0; ks < 2; ++ks) {
            short8 bfr[2], afr[4];
            #pragma unroll
            for (int nt = 0; nt < 2; ++nt)
                bfr[nt] = *(const short8*)((const char*)Bs + swz(wn * 32 + nt * 16 + c, ks * 4 + g));
            #pragma unroll
            for (int mt = 0; mt < 4; ++mt)
                afr[mt] = *(const short8*)((const char*)As + swz(wm * 64 + mt * 16 + c, ks * 4 + g));
            #pragma unroll
            for (int mt = 0; mt < 4; ++mt)
                #pragma unroll
                for (int nt = 0; nt < 2; ++nt)
                    acc[mt][nt] = __builtin_amdgcn_mfma_f32_16x16x32_bf16(
                        afr[mt], bfr[nt], acc[mt][nt], 0, 0, 0);
        }
    }
    __syncthreads();

    float bb[2];
    #pragma unroll
    for (int nt = 0; nt < 2; ++nt) bb[nt] = bias[n0r + wn * 32 + nt * 16 + c];

    const int bidx  = bm >> 11;
    const int sbase = bm & (SS - 1);

    if (proj < 2) {
        f32x4 vr[4][2];
        f32x4 ssp[4];
        #pragma unroll
        for (int mt = 0; mt < 4; ++mt) {
            #pragma unroll
            for (int nt = 0; nt < 2; ++nt)
                #pragma unroll
                for (int j = 0; j < 4; ++j)
                    vr[mt][nt][j] = acc[mt][nt][j] + bb[nt];
            #pragma unroll
            for (int j = 0; j < 4; ++j)
                ssp[mt][j] = vr[mt][0][j]*vr[mt][0][j] + vr[mt][1][j]*vr[mt][1][j];
            #pragma unroll
            for (int j = 0; j < 4; ++j) {
                float s = ssp[mt][j];
                #pragma unroll
                for (int msk = 1; msk < 16; msk <<= 1) s += __shfl_xor(s, msk);
                ssp[mt][j] = s;
            }
        }
        if (c == 0) {
            #pragma unroll
            for (int mt = 0; mt < 4; ++mt)
                #pragma unroll
                for (int j = 0; j < 4; ++j)
                    ssq[wn][wm * 64 + mt * 16 + g * 4 + j] = ssp[mt][j];
        }
        __syncthreads();
        unsigned short* dst = (proj == 0) ? qo : ko;
        // q: fold SCALE * log2(e) so attention uses exp2 (saves a mul per elem)
        const float fold = (proj == 0) ? 0.18033688f : 1.0f;
        #pragma unroll
        for (int mt = 0; mt < 4; ++mt) {
            #pragma unroll
            for (int j = 0; j < 4; ++j) {
                const int rloc = wm * 64 + mt * 16 + g * 4 + j;
                const float ss = ssq[0][rloc] + ssq[1][rloc];
                const float inv = fold / fmaxf(sqrtf(ss), 1e-6f);
                const size_t base =
                    ((size_t)(bidx * HH + h) * SS + sbase + rloc) * DD;
                #pragma unroll
                for (int nt = 0; nt < 2; ++nt)
                    dst[base + wn * 32 + nt * 16 + c] = f2bf(vr[mt][nt][j] * inv);
            }
        }
    } else {
        // V: +bias, transpose via LDS (reuse As as [128 s][64 d]), store [bh][d][s]
        #pragma unroll
        for (int mt = 0; mt < 4; ++mt)
            #pragma unroll
            for (int nt = 0; nt < 2; ++nt)
                #pragma unroll
                for (int j = 0; j < 4; ++j) {
                    const int row = wm * 64 + mt * 16 + g * 4 + j;
                    const int col = wn * 32 + nt * 16 + c;
                    As[row * 64 + col] = (short)f2bf(acc[mt][nt][j] + bb[nt]);
                }
        __syncthreads();
        const int d  = tid & 63;
        const int sb = (tid >> 6) * 32;
        unsigned short* dstp = vo + ((size_t)(bidx * HH + h) * DD + d) * SS + sbase + sb;
        #pragma unroll
        for (int grp = 0; grp < 4; ++grp) {
            unsigned int wds[4];
            #pragma unroll
            for (int e = 0; e < 4; ++e) {
                unsigned short u0 = (unsigned short)As[(sb + grp * 8 + 2 * e)     * 64 + d];
                unsigned short u1 = (unsigned short)As[(sb + grp * 8 + 2 * e + 1) * 64 + d];
                wds[e] = (unsigned int)u0 | ((unsigned int)u1 << 16);
            }
            int4 pk = make_int4((int)wds[0], (int)wds[1], (int)wds[2], (int)wds[3]);
            *(int4*)(dstp + grp * 8) = pk;
        }
    }
}

// stage one 64x64 K-tile + 64x64 V-tile into LDS (4 waves: 2 issues each)
static __device__ __forceinline__ void stage_kv4(
    const unsigned short* __restrict__ kbase, const unsigned short* __restrict__ vbase,
    int s0, short* Kbuf, short* Vbuf, int w, int lr8, int lc8)
{
    #pragma unroll
    for (int i = 0; i < 2; ++i) {     // K: 8 issues, 2/wave
        const int t = w * 2 + i;
        gl16(kbase + (size_t)(s0 + t * 8 + lr8) * DD + lc8 * 8,
             (unsigned short*)Kbuf + t * 512);
    }
    #pragma unroll
    for (int i = 0; i < 2; ++i) {     // V: 8 issues, 2/wave
        const int t = w * 2 + i;
        gl16(vbase + (size_t)(t * 8 + lr8) * SS + s0 + lc8 * 8,
             (unsigned short*)Vbuf + t * 512);
    }
}

// ---------------------------------------------------------------------------
// Kernel 2: flash attention, bf16 MFMA, 2-phase dbuf K/V, 4 waves/block.
// q,k [bh][s][d]; v transposed [bh][d][s]. grid (SS/64, B*H), 256 thr;
// wave owns 16 q-rows (Mrep=1 -> 12 waves/CU, latency-hiding priority).
// q pre-scaled by SCALE*log2e -> P = exp2(sc); no max-tracking (|sc|<=0.19).
// lsum via MFMA with all-ones B (accumulates across tiles in C-regs).
// ---------------------------------------------------------------------------
__global__ __launch_bounds__(256) void attn_mfma_kernel(
    const unsigned short* __restrict__ q, const unsigned short* __restrict__ k,
    const unsigned short* __restrict__ vT, unsigned short* __restrict__ ctx)
{
    __shared__ short Ks[2][64 * 64];     // 16 KB
    __shared__ short Vs[2][64 * 64];     // 16 KB
    __shared__ short Ps[4][16 * 64];     //  8 KB  per-wave [qrow 16][key 64]

    const int tid = threadIdx.x;
    const int bh  = blockIdx.y;
    const int w   = tid >> 6;
    const int l   = tid & 63;
    const int c   = l & 15;
    const int g   = l >> 4;
    const int lr8 = l >> 3;
    const int lc8 = (l & 7) ^ lr8;
    const int qr0 = blockIdx.x * 64 + w * 16;

    const unsigned short* kbase = k  + (size_t)bh * SS * DD;
    const unsigned short* vbase = vT + (size_t)bh * DD * SS;

    // Q A-frags in registers, reused across all KV tiles
    short8 aq[2];
    {
        const unsigned short* qg = q + ((size_t)bh * SS + qr0 + c) * DD;
        aq[0] = *(const short8*)(qg + g * 8);
        aq[1] = *(const short8*)(qg + 32 + g * 8);
    }
    // all-ones bf16 B-frag for row-sum MFMA
    const short one_bf = (short)0x3F80;
    short8 ones = {one_bf, one_bf, one_bf, one_bf, one_bf, one_bf, one_bf, one_bf};

    short* Psw = Ps[w];
    f32x4 o[4] = {};
    f32x4 lacc = {0.f, 0.f, 0.f, 0.f};

    stage_kv4(kbase, vbase, 0, Ks[0], Vs[0], w, lr8, lc8);
    __syncthreads();                         // drain tile-0 loads

    for (int t = 0; t < SS / 64; ++t) {
        const int cur = t & 1;
        if (t + 1 < SS / 64)                 // prefetch next KV tile (async)
            stage_kv4(kbase, vbase, (t + 1) * 64, Ks[cur ^ 1], Vs[cur ^ 1], w, lr8, lc8);

        // QK^T: rows=q (g*4+j), cols=key (c)
        f32x4 sc[4] = {};
        #pragma unroll
        for (int ks = 0; ks < 2; ++ks)
            #pragma unroll
            for (int nt = 0; nt < 4; ++nt) {
                short8 kf = *(const short8*)((const char*)Ks[cur] + swz(nt * 16 + c, ks * 4 + g));
                sc[nt] = __builtin_amdgcn_mfma_f32_16x16x32_bf16(aq[ks], kf, sc[nt], 0, 0, 0);
            }

        // P = exp2(sc) (log2e folded into q), -> bf16 -> per-wave LDS
        #pragma unroll
        for (int nt = 0; nt < 4; ++nt)
            #pragma unroll
            for (int j = 0; j < 4; ++j) {
                const float p = __builtin_exp2f(sc[nt][j]);
                const int row = g * 4 + j;
                const int ch  = (nt * 2 + (c >> 3)) ^ (row & 7);
                Psw[row * 64 + (ch << 3) + (c & 7)] = (short)f2bf(p);
            }

        // PV + denominator (lacc += P . ones)
        #pragma unroll
        for (int ks = 0; ks < 2; ++ks) {
            short8 pa = *(const short8*)((const char*)Psw + swz(c, ks * 4 + g));
            lacc = __builtin_amdgcn_mfma_f32_16x16x32_bf16(pa, ones, lacc, 0, 0, 0);
            #pragma unroll
            for (int dt = 0; dt < 4; ++dt) {
                short8 vf = *(const short8*)((const char*)Vs[cur] + swz(dt * 16 + c, ks * 4 + g));
                o[dt] = __builtin_amdgcn_mfma_f32_16x16x32_bf16(pa, vf, o[dt], 0, 0, 0);
            }
        }
        __syncthreads();   // one barrier/tile: drains prefetch AFTER compute
    }

    // epilogue: divide by denom (lacc cols all equal), store ctx bf16 [b][s][e]
    const int bidx = bh / HH, h = bh % HH;
    #pragma unroll
    for (int j = 0; j < 4; ++j) {
        const float inv = 1.0f / lacc[j];
        const int sg = qr0 + g * 4 + j;
        unsigned short* op = ctx + ((size_t)bidx * SS + sg) * EE + h * DD + c;
        #pragma unroll
        for (int dt = 0; dt < 4; ++dt)
            op[dt * 16] = f2bf(o[dt][j] * inv);
    }
}

// ---------------------------------------------------------------------------
// Kernel 3: output projection, MFMA, single-buffered (round-5 form).
// out = ctx(bf16) @ Wo.T + bo (fp32 out). grid (MM/128, EE/64).
// ---------------------------------------------------------------------------
__global__ __launch_bounds__(256) void out_mfma_kernel(
    const unsigned short* __restrict__ A, const unsigned short* __restrict__ W,
    const float* __restrict__ bias, float* __restrict__ out)
{
    __shared__ short As[128 * 64];
    __shared__ short Bs[64 * 64];

    const int tid = threadIdx.x;
    const int bm  = blockIdx.x * 128;
    const int n0  = blockIdx.y * 64;

    const int w  = tid >> 6;
    const int l  = tid & 63;
    const int c  = l & 15;
    const int g  = l >> 4;
    const int wm = w >> 1;
    const int wn = w & 1;
    const int lr8 = l >> 3;
    const int lc8 = (l & 7) ^ lr8;

    f32x4 acc[4][2] = {};

    for (int kt = 0; kt < EE; kt += 64) {
        __syncthreads();
        #pragma unroll
        for (int i = 0; i < 4; ++i) {
            const int t = w * 4 + i;
            gl16(A + (size_t)(bm + t * 8 + lr8) * EE + kt + lc8 * 8,
                 (unsigned short*)As + t * 512);
        }
        #pragma unroll
        for (int i = 0; i < 2; ++i) {
            const int t = w * 2 + i;
            gl16(W + (size_t)(n0 + t * 8 + lr8) * EE + kt + lc8 * 8,
                 (unsigned short*)Bs + t * 512);
        }
        __syncthreads();

        #pragma unroll
        for (int ks = 0; ks < 2; ++ks) {
            short8 bfr[2], afr[4];
            #pragma unroll
            for (int nt = 0; nt < 2; ++nt)
                bfr[nt] = *(const short8*)((const char*)Bs + swz(wn * 32 + nt * 16 + c, ks * 4 + g));
            #pragma unroll
            for (int mt = 0; mt < 4; ++mt)
                afr[mt] = *(const short8*)((const char*)As + swz(wm * 64 + mt * 16 + c, ks * 4 + g));
            #pragma unroll
            for (int mt = 0; mt < 4; ++mt)
                #pragma unroll
                for (int nt = 0; nt < 2; ++nt)
                    acc[mt][nt] = __builtin_amdgcn_mfma_f32_16x16x32_bf16(
                        afr[mt], bfr[nt], acc[mt][nt], 0, 0, 0);
        }
    }

    float bb[2];
    #pragma unroll
    for (int nt = 0; nt < 2; ++nt) bb[nt] = bias[n0 + wn * 32 + nt * 16 + c];

    #pragma unroll
    for (int mt = 0; mt < 4; ++mt)
        #pragma unroll
        for (int j = 0; j < 4; ++j) {
            const int row = bm + wm * 64 + mt * 16 + g * 4 + j;
            float* op = out + (size_t)row * EE + n0 + wn * 32 + c;
            #pragma unroll
            for (int nt = 0; nt < 2; ++nt)
                op[nt * 16] = acc[mt][nt][j] + bb[nt];
        }
}

// ---------------------------------------------------------------------------
extern "C" void kernel_launch(void* const* d_in, const int* in_sizes, int n_in,
                              void* d_out, int out_size, void* d_ws, size_t ws_size,
                              hipStream_t stream)
{
    const float* query = (const float*)d_in[0];
    const float* key   = (const float*)d_in[1];
    const float* value = (const float*)d_in[2];
    const float* Wq = (const float*)d_in[3];
    const float* bq = (const float*)d_in[4];
    const float* Wk = (const float*)d_in[5];
    const float* bk = (const float*)d_in[6];
    const float* Wv = (const float*)d_in[7];
    const float* bv = (const float*)d_in[8];
    const float* Wo = (const float*)d_in[9];
    const float* bo = (const float*)d_in[10];
    float* out = (float*)d_out;

    // ws: xqc/xkc/xvc (bf16 inputs), q/k/vT (bf16 heads), W's bf16.
    // ctx aliases xqc (qkv consumed it before attn writes; stream-ordered).
    unsigned short* xqc  = (unsigned short*)d_ws;
    unsigned short* xkc  = xqc  + NT;
    unsigned short* xvc  = xkc  + NT;
    unsigned short* qws  = xvc  + NT;
    unsigned short* kws  = qws  + NT;
    unsigned short* vtws = kws  + NT;
    unsigned short* wqc  = vtws + NT;
    unsigned short* wkc  = wqc  + NW;
    unsigned short* wvc  = wkc  + NW;
    unsigned short* woc  = wvc  + NW;
    unsigned short* ctx  = xqc;          // alias

    const int cvt_blocks = (3 * (NT / 4) + 4 * (NW / 4)) / 256;   // 11520
    cvt_all_kernel<<<dim3(cvt_blocks), 256, 0, stream>>>(
        query, key, value, Wq, Wk, Wv, Wo,
        xqc, xkc, xvc, wqc, wkc, wvc, woc);
    qkv_mfma_kernel<<<dim3(MM / 128, 36), 256, 0, stream>>>(
        xqc, xkc, xvc, wqc, bq, wkc, bk, wvc, bv, qws, kws, vtws);
    attn_mfma_kernel<<<dim3(SS / 64, BB * HH), 256, 0, stream>>>(
        qws, kws, vtws, ctx);
    out_mfma_kernel<<<dim3(MM / 128, EE / 64), 256, 0, stream>>>(
        ctx, woc, bo, out);
}